// Round 12
// baseline (425.291 us; speedup 1.0000x reference)
//
#include <hip/hip_runtime.h>

#define T_SEQ 4096
#define D_MODEL 768
#define N_HEADS 12
#define HEAD_DIM 64
#define FF_DIM 3072
#define QKV_LD 2304    // 3*D_MODEL
#define AG_LD  6144    // 2*FF_DIM
#define KCHUNK 8       // k-tiles (of 64 keys) per attention block
#define PSTRIDE2 8320  // 128*64 + 128 floats per partial

typedef __bf16 bf16x8 __attribute__((ext_vector_type(8)));
typedef float  f32x4  __attribute__((ext_vector_type(4)));

__device__ __forceinline__ unsigned short f2bf(float f) {
    unsigned int u = __float_as_uint(f);
    u += 0x7FFFu + ((u >> 16) & 1u);
    return (unsigned short)(u >> 16);
}
__device__ __forceinline__ float bf2f(unsigned short s) {
    return __uint_as_float(((unsigned int)s) << 16);
}
__device__ __forceinline__ f32x4 mfma16(bf16x8 a, bf16x8 b, f32x4 c) {
    return __builtin_amdgcn_mfma_f32_16x16x32_bf16(a, b, c, 0, 0, 0);
}
// async global->LDS, 16B per lane; LDS dest = wave-uniform base + lane*16
__device__ __forceinline__ void gload_lds16(const unsigned short* g, unsigned short* l) {
    __builtin_amdgcn_global_load_lds(
        (const __attribute__((address_space(1))) unsigned int*)g,
        (__attribute__((address_space(3))) unsigned int*)l,
        16, 0, 0);
}

// ---------------------------------------------------------------------------
// Fused prep: weight transposes (jobs 0..9215) + interleaved bias pack
// (9216..9227) + LayerNorm1 (9228..13323). One launch, independent jobs.
// ---------------------------------------------------------------------------
__global__ __launch_bounds__(256) void prep_fused(const float* __restrict__ Wq,
                                                  const float* __restrict__ Wk,
                                                  const float* __restrict__ Wv,
                                                  const float* __restrict__ Wo,
                                                  const float* __restrict__ w1,
                                                  const float* __restrict__ w2,
                                                  const float* __restrict__ w3,
                                                  unsigned short* __restrict__ Wqkv_t,
                                                  unsigned short* __restrict__ Wo_t,
                                                  unsigned short* __restrict__ W12_t,
                                                  unsigned short* __restrict__ W3_t,
                                                  const float* __restrict__ b1,
                                                  const float* __restrict__ b2,
                                                  float* __restrict__ b12,
                                                  const float* __restrict__ x,
                                                  const float* __restrict__ g1,
                                                  const float* __restrict__ s1,
                                                  unsigned short* __restrict__ hout) {
    __shared__ float tile[32][33];
    __shared__ float red[4];
    __shared__ float mv[2];
    const int b = blockIdx.x;
    const int tid = threadIdx.x;

    if (b >= 9228) {                      // --- LayerNorm1 on row (b-9228) ---
        const int row = b - 9228;
        const float* xr = x + (size_t)row * D_MODEL;
        unsigned short* orow = hout + (size_t)row * D_MODEL;
        float v0 = xr[tid], v1 = xr[tid + 256], v2 = xr[tid + 512];
        float sum = v0 + v1 + v2;
        const int lane = tid & 63, wv = tid >> 6;
        #pragma unroll
        for (int off = 32; off > 0; off >>= 1) sum += __shfl_down(sum, off, 64);
        if (lane == 0) red[wv] = sum;
        __syncthreads();
        if (tid == 0) mv[0] = (red[0] + red[1] + red[2] + red[3]) * (1.0f / D_MODEL);
        __syncthreads();
        const float mean = mv[0];
        float d0 = v0 - mean, d1 = v1 - mean, d2 = v2 - mean;
        float sq = d0 * d0 + d1 * d1 + d2 * d2;
        #pragma unroll
        for (int off = 32; off > 0; off >>= 1) sq += __shfl_down(sq, off, 64);
        if (lane == 0) red[wv] = sq;
        __syncthreads();
        if (tid == 0) mv[1] = (red[0] + red[1] + red[2] + red[3]) * (1.0f / D_MODEL);
        __syncthreads();
        const float rs = rsqrtf(mv[1] + 1e-5f);
        orow[tid]       = f2bf(g1[tid]       * d0 * rs + s1[tid]);
        orow[tid + 256] = f2bf(g1[tid + 256] * d1 * rs + s1[tid + 256]);
        orow[tid + 512] = f2bf(g1[tid + 512] * d2 * rs + s1[tid + 512]);
        return;
    }
    if (b >= 9216) {                      // --- bias pack ---
        const int n = (b - 9216) * 256 + tid;
        if (n < FF_DIM) {
            b12[(n >> 4) * 32 + (n & 15)] = b1[n];
            b12[(n >> 4) * 32 + 16 + (n & 15)] = b2[n];
        }
        return;
    }

    // --- weight transpose jobs ---
    const float* W; unsigned short* Wt;
    int K, N, off, ilv, bx, by;
    if (b < 2304) {                       // jobs 0-3: 576 blocks each (24x24)
        const int j = b / 576, lb = b % 576;
        bx = lb % 24; by = lb / 24;
        K = 768; N = 768; ilv = 0;
        if (j == 0)      { W = Wq; Wt = Wqkv_t; off = 0; }
        else if (j == 1) { W = Wk; Wt = Wqkv_t; off = 768; }
        else if (j == 2) { W = Wv; Wt = Wqkv_t; off = 1536; }
        else             { W = Wo; Wt = Wo_t;   off = 0; }
    } else if (b < 6912) {                // jobs 4-5: 2304 blocks each (96x24)
        const int j = (b - 2304) / 2304, lb = (b - 2304) % 2304;
        bx = lb % 96; by = lb / 96;
        K = 768; N = 3072; ilv = 1;
        W = j ? w2 : w1; Wt = W12_t; off = j ? 16 : 0;
    } else {                              // job 6: 2304 blocks (24x96)
        const int lb = b - 6912;
        bx = lb % 24; by = lb / 24;
        K = 3072; N = 768; ilv = 0;
        W = w3; Wt = W3_t; off = 0;
    }

    const int tx = tid & 31, ty = tid >> 5;  // 32 x 8
    const int n0 = bx * 32, k0 = by * 32;
    #pragma unroll
    for (int s = 0; s < 32; s += 8)
        tile[ty + s][tx] = W[(size_t)(k0 + ty + s) * N + n0 + tx];
    __syncthreads();
    #pragma unroll
    for (int s = 0; s < 32; s += 8) {
        const int nn = n0 + ty + s;
        const int R = ilv ? ((nn >> 4) * 32 + off + (nn & 15)) : (off + nn);
        Wt[(size_t)R * K + k0 + tx] = f2bf(tile[tx][ty + s]);
    }
}

// ---------------------------------------------------------------------------
// V transpose (bf16) with per-64-tile KEY-SLOT PERMUTATION:
// Vt[c][t0 + s] = qkv[t0 + kl(s)][1536+c],  kl(s) = (s&3)*16 + (s>>2).
// Matches the P slot assignment s = 4r + ni in softmax_step2.
// ---------------------------------------------------------------------------
__global__ __launch_bounds__(256) void vtrans_kernel(const unsigned short* __restrict__ qkv,
                                                     unsigned short* __restrict__ Vt) {
    __shared__ unsigned short tile[64][72];
    const int t0 = blockIdx.x * 64;   // seq
    const int c0 = blockIdx.y * 64;   // feature
    const int tr = threadIdx.x >> 3;         // 0..31
    const int tc = (threadIdx.x & 7) * 8;    // 0,8,..,56
    #pragma unroll
    for (int s = 0; s < 2; ++s) {
        uint4 v = *(const uint4*)(qkv + (size_t)(t0 + tr + s * 32) * QKV_LD + 2 * D_MODEL + c0 + tc);
        *(uint4*)(&tile[tr + s * 32][tc]) = v;
    }
    __syncthreads();
    #pragma unroll
    for (int sb = 0; sb < 2; ++sb) {
        const int cr = tr + sb * 32;
        unsigned short ob[8];
        #pragma unroll
        for (int j = 0; j < 8; ++j) {
            const int s = tc + j;
            ob[j] = tile[(s & 3) * 16 + (s >> 2)][cr];
        }
        *(uint4*)(Vt + (size_t)(c0 + cr) * T_SEQ + t0 + tc) = *(uint4*)ob;
    }
}

// ---------------------------------------------------------------------------
// LayerNorm (fp32 in, bf16 out) — used for LN2
// ---------------------------------------------------------------------------
__global__ __launch_bounds__(256) void ln_kernel(const float* __restrict__ x,
                                                 const float* __restrict__ g,
                                                 const float* __restrict__ b,
                                                 unsigned short* __restrict__ o) {
    const int row = blockIdx.x;
    const float* xr = x + (size_t)row * D_MODEL;
    unsigned short* orow = o + (size_t)row * D_MODEL;
    const int tid = threadIdx.x;

    float v0 = xr[tid], v1 = xr[tid + 256], v2 = xr[tid + 512];
    float sum = v0 + v1 + v2;

    __shared__ float red[4];
    __shared__ float mv[2];
    const int lane = tid & 63, wv = tid >> 6;

    #pragma unroll
    for (int off = 32; off > 0; off >>= 1) sum += __shfl_down(sum, off, 64);
    if (lane == 0) red[wv] = sum;
    __syncthreads();
    if (tid == 0) mv[0] = (red[0] + red[1] + red[2] + red[3]) * (1.0f / D_MODEL);
    __syncthreads();
    const float mean = mv[0];

    float d0 = v0 - mean, d1 = v1 - mean, d2 = v2 - mean;
    float sq = d0 * d0 + d1 * d1 + d2 * d2;
    #pragma unroll
    for (int off = 32; off > 0; off >>= 1) sq += __shfl_down(sq, off, 64);
    if (lane == 0) red[wv] = sq;
    __syncthreads();
    if (tid == 0) mv[1] = (red[0] + red[1] + red[2] + red[3]) * (1.0f / D_MODEL);
    __syncthreads();
    const float rs = rsqrtf(mv[1] + 1e-5f);

    orow[tid]       = f2bf(g[tid]       * d0 * rs + b[tid]);
    orow[tid + 256] = f2bf(g[tid + 256] * d1 * rs + b[tid + 256]);
    orow[tid + 512] = f2bf(g[tid + 512] * d2 * rs + b[tid + 512]);
}

// ---------------------------------------------------------------------------
// bf16 MFMA GEMM, templated tile. BM=WY*MI*16, BN=WX*NI*16, BK=32, 256 thr,
// async global_load_lds staging, double-buffered, one barrier per iter.
// EPI=0: C = acc + bias + res -> Cf (fp32) or Cb (bf16), pitch N.
// EPI=1: SwiGLU epilogue on 16-col-interleaved B -> Cb, pitch N/2.
// ---------------------------------------------------------------------------
template<int BM, int BN, int WY, int WX, int MI, int NI, int EPI>
__global__ __launch_bounds__(256) void mfma_gemm(const unsigned short* __restrict__ A,
                                                 const unsigned short* __restrict__ Bt,
                                                 const float* __restrict__ bias,
                                                 const float* __restrict__ res,
                                                 float* __restrict__ Cf,
                                                 unsigned short* __restrict__ Cb,
                                                 int M, int N, int K) {
    constexpr int CA = BM * 4;
    constexpr int CT = BM * 4 + BN * 4;
    constexpr int SA = CA / 256;
    constexpr int ST = CT / 256;
    __shared__ unsigned short S[2][CT * 8];

    const int t = threadIdx.x;
    const int bn = blockIdx.x * BN;
    const int bm = blockIdx.y * BM;
    const int w = t >> 6, lane = t & 63;
    const int wy = w / WX, wx = w % WX;
    const int quad = lane >> 4, r = lane & 15;
    const int rc = lane & 15, kq = (lane >> 4) & 3;

    const unsigned short* gp[ST];
    #pragma unroll
    for (int s = 0; s < ST; ++s) {
        if (s < SA) gp[s] = A  + (size_t)(bm + (s * 4 + w) * 16 + rc) * K + kq * 8;
        else        gp[s] = Bt + (size_t)(bn + ((s - SA) * 4 + w) * 16 + rc) * K + kq * 8;
    }

    f32x4 acc[MI][NI];
    const f32x4 fz = {0.f, 0.f, 0.f, 0.f};
    #pragma unroll
    for (int i = 0; i < MI; ++i)
        #pragma unroll
        for (int j = 0; j < NI; ++j) acc[i][j] = fz;

    #pragma unroll
    for (int s = 0; s < ST; ++s)
        gload_lds16(gp[s], &S[0][(s * 256 + w * 64) * 8]);

    const int niter = K >> 5;
    for (int it = 0; it < niter; ++it) {
        const int buf = it & 1;
        __syncthreads();
        if (it + 1 < niter) {
            const int ko = (it + 1) * 32;
            #pragma unroll
            for (int s = 0; s < ST; ++s)
                gload_lds16(gp[s] + ko, &S[buf ^ 1][(s * 256 + w * 64) * 8]);
        }

        bf16x8 af[MI], bfr[NI];
        #pragma unroll
        for (int mi = 0; mi < MI; ++mi)
            af[mi] = *(const bf16x8*)(&S[buf][((wy * MI + mi) * 64 + lane) * 8]);
        #pragma unroll
        for (int ni = 0; ni < NI; ++ni)
            bfr[ni] = *(const bf16x8*)(&S[buf][(CA + (wx * NI + ni) * 64 + lane) * 8]);
        #pragma unroll
        for (int mi = 0; mi < MI; ++mi)
            #pragma unroll
            for (int ni = 0; ni < NI; ++ni)
                acc[mi][ni] = mfma16(af[mi], bfr[ni], acc[mi][ni]);
    }

    float bv[NI];
    #pragma unroll
    for (int ni = 0; ni < NI; ++ni)
        bv[ni] = bias ? bias[bn + (wx * NI + ni) * 16 + r] : 0.0f;

    if (EPI == 0) {
        #pragma unroll
        for (int mi = 0; mi < MI; ++mi) {
            #pragma unroll
            for (int i = 0; i < 4; ++i) {
                const int m = bm + (wy * MI + mi) * 16 + quad * 4 + i;
                #pragma unroll
                for (int ni = 0; ni < NI; ++ni) {
                    const int n = bn + (wx * NI + ni) * 16 + r;
                    float v = acc[mi][ni][i] + bv[ni];
                    if (res) v += res[(size_t)m * N + n];
                    if (Cf) Cf[(size_t)m * N + n] = v;
                    else    Cb[(size_t)m * N + n] = f2bf(v);
                }
            }
        }
    } else {
        #pragma unroll
        for (int mi = 0; mi < MI; ++mi) {
            #pragma unroll
            for (int i = 0; i < 4; ++i) {
                const int m = bm + (wy * MI + mi) * 16 + quad * 4 + i;
                #pragma unroll
                for (int p = 0; p < NI / 2; ++p) {
                    float a = acc[mi][2 * p][i] + bv[2 * p];
                    float g = acc[mi][2 * p + 1][i] + bv[2 * p + 1];
                    float uu = a / (1.0f + __expf(-a)) * g;
                    const int n = (bn >> 1) + wx * (NI / 2) * 16 + p * 16 + r;
                    Cb[(size_t)m * (N >> 1) + n] = f2bf(uu);
                }
            }
        }
    }
}

// ---------------------------------------------------------------------------
// Softmax step, 2 M-fragments (32 q-rows/wave), fixed-max: p = exp(s),
// masked -> 0. b64 P writes, XOR bank swizzle (round 11 scheme), per-mi
// 1024-short region. V staged with matching key permutation (vtrans).
// ---------------------------------------------------------------------------
template <bool DIAG>
__device__ __forceinline__ void softmax_step2(const f32x4 sacc[2][4],
                                              unsigned short* __restrict__ Pw,
                                              int k0, int qg0, int r, int quad) {
    const int rp = r >> 1;
    const int cbase = (r >> 3) * 64 + ((r >> 1) & 3) * 16;
    #pragma unroll
    for (int mi = 0; mi < 2; ++mi) {
        unsigned short* Pm = Pw + mi * 1024;
        #pragma unroll
        for (int i = 0; i < 4; ++i) {
            unsigned int pk[2];
            #pragma unroll
            for (int ni = 0; ni < 4; ++ni) {
                float p = __expf(sacc[mi][ni][i]);
                if (DIAG) { if (k0 + ni * 16 + r > qg0 + mi * 16 + i) p = 0.0f; }
                const unsigned int pb = (__float_as_uint(p) + 0x8000u) >> 16;
                if (ni & 1) pk[ni >> 1] |= pb << 16;
                else        pk[ni >> 1] = pb;
            }
            const int rrp = (quad * 4 + i) ^ rp;
            uint2 wv; wv.x = pk[0]; wv.y = pk[1];
            *(uint2*)(&Pm[(cbase + rrp) * 8 + 4 * (r & 1)]) = wv;
        }
    }
}

// ---------------------------------------------------------------------------
// Flash attention partial: 128 q-rows per block (wave = 32 rows), K-split
// into chunks of <=8 k-tiles. Each staged K/V tile feeds 36 MFMA (2x the
// 64-row version). Partial O (fp32 128x64) + l (fp32 128) to workspace.
// Per head: q-tile qt (128 rows) has ceil((2qt+2)/8) chunks -> 144 blocks.
// ---------------------------------------------------------------------------
__global__ __launch_bounds__(256) void attn_partial(const unsigned short* __restrict__ qkv,
                                                    const unsigned short* __restrict__ Vt,
                                                    float* __restrict__ part) {
    const int h = blockIdx.y;
    int b = (int)blockIdx.x, qt = 31, ci = 0;
    for (int q = 31; q >= 0; --q) {          // longest q-tiles first
        const int nc = (2 * q + 9) >> 3;     // ceil((2q+2)/8)
        if (b < nc) { qt = q; ci = b; break; }
        b -= nc;
    }
    const int q0 = qt * 128;
    const int kb = ci * KCHUNK;              // first k-tile of this chunk
    const int nt = min(KCHUNK, 2 * qt + 2 - kb);

    const int t = threadIdx.x;
    const int w = t >> 6, lane = t & 63;
    const int quad = lane >> 4, r = lane & 15;

    __shared__ unsigned short Ks[2][4096];
    __shared__ unsigned short Vs[2][4096];
    __shared__ unsigned short Ps[4][2048];

    // Q fragments (scale 1/8 folded in): rows q0 + w*32 + mi*16 + r
    bf16x8 aq[2][2];   // [ks][mi]
    #pragma unroll
    for (int mi = 0; mi < 2; ++mi) {
        const unsigned short* qp = qkv + (size_t)(q0 + w * 32 + mi * 16 + r) * QKV_LD + h * 64 + quad * 8;
        uint4 q0v = *(const uint4*)(qp);
        uint4 q1v = *(const uint4*)(qp + 32);
        const unsigned short* p0 = (const unsigned short*)&q0v;
        const unsigned short* p1 = (const unsigned short*)&q1v;
        #pragma unroll
        for (int j = 0; j < 8; ++j) {
            aq[0][mi][j] = (__bf16)(bf2f(p0[j]) * 0.125f);
            aq[1][mi][j] = (__bf16)(bf2f(p1[j]) * 0.125f);
        }
    }

    bf16x8 ones;
    #pragma unroll
    for (int j = 0; j < 8; ++j) ones[j] = (__bf16)1.0f;

    // per-lane staging sources (chunk c = s*256 + w*64 + lane), offset by kb
    const int rc = lane & 15, qc = (lane >> 4) & 3;
    const unsigned short* kg0 = qkv + (size_t)(kb * 64 + w * 16 + rc) * QKV_LD + D_MODEL + h * 64 + qc * 8;
    const unsigned short* kg1 = kg0 + 32;
    const unsigned short* vg0 = Vt + (size_t)(h * 64 + w * 16 + rc) * T_SEQ + kb * 64 + qc * 8;
    const unsigned short* vg1 = vg0 + 32;
    const int l0 = (w * 64) * 8, l1 = (256 + w * 64) * 8;

    const f32x4 fz = {0.f, 0.f, 0.f, 0.f};
    f32x4 acc_o[2][4] = {{fz, fz, fz, fz}, {fz, fz, fz, fz}};
    f32x4 acc_l[2] = {fz, fz};
    const int qg0 = q0 + w * 32 + quad * 4;

    gload_lds16(kg0, &Ks[0][l0]);
    gload_lds16(kg1, &Ks[0][l1]);
    gload_lds16(vg0, &Vs[0][l0]);
    gload_lds16(vg1, &Vs[0][l1]);

    for (int lt = 0; lt < nt; ++lt) {
        const int kt = kb + lt;
        const int buf = lt & 1;
        __syncthreads();
        if (lt + 1 < nt) {
            const size_t kofs = (size_t)(lt + 1) * 64;
            gload_lds16(kg0 + kofs * QKV_LD, &Ks[buf ^ 1][l0]);
            gload_lds16(kg1 + kofs * QKV_LD, &Ks[buf ^ 1][l1]);
            gload_lds16(vg0 + kofs, &Vs[buf ^ 1][l0]);
            gload_lds16(vg1 + kofs, &Vs[buf ^ 1][l1]);
        }

        // S = (Q/8) @ K^T : 16 MFMA off 8 shared K reads
        f32x4 sacc[2][4] = {{fz, fz, fz, fz}, {fz, fz, fz, fz}};
        #pragma unroll
        for (int ks = 0; ks < 2; ++ks)
            #pragma unroll
            for (int ni = 0; ni < 4; ++ni) {
                bf16x8 bk = *(const bf16x8*)(&Ks[buf][((ks * 4 + ni) * 64 + lane) * 8]);
                sacc[0][ni] = mfma16(aq[ks][0], bk, sacc[0][ni]);
                sacc[1][ni] = mfma16(aq[ks][1], bk, sacc[1][ni]);
            }

        const int k0 = kt * 64;
        if (kt >= 2 * qt)
            softmax_step2<true >(sacc, Ps[w], k0, qg0, r, quad);
        else
            softmax_step2<false>(sacc, Ps[w], k0, qg0, r, quad);

        // O += P @ V ; l += P @ 1 : 20 MFMA off 8 shared V reads
        const int kqr = lane >> 4, rrr = lane & 15;
        #pragma unroll
        for (int ks = 0; ks < 2; ++ks) {
            const int pc = ks * 64 + kqr * 16 + (rrr ^ (ks * 4 + kqr));
            bf16x8 ap0 = *(const bf16x8*)(&Ps[w][pc * 8]);
            bf16x8 ap1 = *(const bf16x8*)(&Ps[w][1024 + pc * 8]);
            #pragma unroll
            for (int nd = 0; nd < 4; ++nd) {
                bf16x8 bv = *(const bf16x8*)(&Vs[buf][((ks * 4 + nd) * 64 + lane) * 8]);
                acc_o[0][nd] = mfma16(ap0, bv, acc_o[0][nd]);
                acc_o[1][nd] = mfma16(ap1, bv, acc_o[1][nd]);
            }
            acc_l[0] = mfma16(ap0, ones, acc_l[0]);
            acc_l[1] = mfma16(ap1, ones, acc_l[1]);
        }
    }

    // write fp32 partial: O[128][64] then l[128]
    float* pb = part + ((size_t)(qt * N_HEADS + h) * KCHUNK + ci) * PSTRIDE2;
    #pragma unroll
    for (int mi = 0; mi < 2; ++mi) {
        #pragma unroll
        for (int i = 0; i < 4; ++i) {
            const int row = w * 32 + mi * 16 + quad * 4 + i;
            #pragma unroll
            for (int nd = 0; nd < 4; ++nd)
                pb[row * 64 + nd * 16 + r] = acc_o[mi][nd][i];
            if (r == 0) pb[8192 + row] = acc_l[mi][i];
        }
    }
}

// ---------------------------------------------------------------------------
// Merge partials: ctx[q0+row][h*64+c] = (sum O) / (sum l). grid (32, 12).
// thread -> row = t>>1, 32-col half = (t&1)*32.
// ---------------------------------------------------------------------------
__global__ __launch_bounds__(256) void attn_merge(const float* __restrict__ part,
                                                  unsigned short* __restrict__ ctx) {
    const int qt = blockIdx.x, h = blockIdx.y;
    const int nc = (2 * qt + 9) >> 3;
    const int t = threadIdx.x;
    const int row = t >> 1, cg = (t & 1) * 32;

    float o[32];
    #pragma unroll
    for (int j = 0; j < 32; ++j) o[j] = 0.0f;
    float l = 0.0f;

    for (int ci = 0; ci < nc; ++ci) {
        const float* pb = part + ((size_t)(qt * N_HEADS + h) * KCHUNK + ci) * PSTRIDE2;
        l += pb[8192 + row];
        #pragma unroll
        for (int j = 0; j < 32; j += 4) {
            float4 v = *(const float4*)(pb + row * 64 + cg + j);
            o[j] += v.x; o[j + 1] += v.y; o[j + 2] += v.z; o[j + 3] += v.w;
        }
    }
    const float inv = 1.0f / l;
    unsigned short ob[32];
    #pragma unroll
    for (int j = 0; j < 32; ++j) ob[j] = f2bf(o[j] * inv);
    unsigned short* dst = ctx + (size_t)(qt * 128 + row) * D_MODEL + h * 64 + cg;
    #pragma unroll
    for (int j = 0; j < 32; j += 8)
        *(uint4*)(dst + j) = *(uint4*)(ob + j);
}

// ---------------------------------------------------------------------------
// launch
// ---------------------------------------------------------------------------
extern "C" void kernel_launch(void* const* d_in, const int* in_sizes, int n_in,
                              void* d_out, int out_size, void* d_ws, size_t ws_size,
                              hipStream_t stream) {
    const float* x  = (const float*)d_in[0];
    const float* Wq = (const float*)d_in[1];
    const float* Wk = (const float*)d_in[2];
    const float* Wv = (const float*)d_in[3];
    const float* Wo = (const float*)d_in[4];
    const float* bo = (const float*)d_in[5];
    const float* w1 = (const float*)d_in[6];
    const float* b1 = (const float*)d_in[7];
    const float* w2 = (const float*)d_in[8];
    const float* b2 = (const float*)d_in[9];
    const float* w3 = (const float*)d_in[10];
    const float* b3 = (const float*)d_in[11];
    const float* g1 = (const float*)d_in[12];
    const float* s1 = (const float*)d_in[13];
    const float* g2 = (const float*)d_in[14];
    const float* s2 = (const float*)d_in[15];
    float* out = (float*)d_out;

    const size_t TD = (size_t)T_SEQ * D_MODEL;

    char* p = (char*)d_ws;
    auto alloc = [&](size_t bytes) { char* r = p; p += (bytes + 255) & ~(size_t)255; return r; };
    // persistent region (live across attention)
    unsigned short* qkv    = (unsigned short*)alloc((size_t)T_SEQ * QKV_LD * 2);
    unsigned short* Vtb    = (unsigned short*)alloc((size_t)D_MODEL * T_SEQ * 2);
    unsigned short* ctx    = (unsigned short*)alloc(TD * 2);
    unsigned short* Wqkv_t = (unsigned short*)alloc((size_t)QKV_LD * D_MODEL * 2);
    unsigned short* Wo_t   = (unsigned short*)alloc((size_t)D_MODEL * D_MODEL * 2);
    unsigned short* W12_t  = (unsigned short*)alloc((size_t)AG_LD * D_MODEL * 2);
    unsigned short* W3_t   = (unsigned short*)alloc((size_t)D_MODEL * FF_DIM * 2);
    float*          b12    = (float*)alloc((size_t)AG_LD * 4);
    // overlay region: part (attn_partial->attn_merge) aliases {h, x2, h2, u},
    // whose lifetimes are disjoint from part's (h dead after QKV; x2/h2/u
    // written only after merge).
    const size_t part_bytes = (size_t)32 * N_HEADS * KCHUNK * PSTRIDE2 * 4;   // 102.2 MB
    char* R = alloc(part_bytes);
    float*          part = (float*)R;
    unsigned short* h    = (unsigned short*)R;                        // TD*2
    float*          x2   = (float*)(R + ((TD * 2 + 255) & ~(size_t)255));
    unsigned short* h2   = (unsigned short*)((char*)x2 + ((TD * 4 + 255) & ~(size_t)255));
    unsigned short* u    = (unsigned short*)((char*)h2 + ((TD * 2 + 255) & ~(size_t)255));

    // --- fused prep: weight transposes + bias pack + LN1 ---
    prep_fused<<<13324, 256, 0, stream>>>(Wq, Wk, Wv, Wo, w1, w2, w3,
                                          Wqkv_t, Wo_t, W12_t, W3_t,
                                          b1, b2, b12, x, g1, s1, h);

    // QKV: [T,768] @ [768,2304]
    mfma_gemm<128, 128, 2, 2, 4, 4, 0><<<dim3(QKV_LD / 128, T_SEQ / 128), 256, 0, stream>>>(
        h, Wqkv_t, nullptr, nullptr, nullptr, qkv, T_SEQ, QKV_LD, D_MODEL);

    vtrans_kernel<<<dim3(T_SEQ / 64, D_MODEL / 64), 256, 0, stream>>>(qkv, Vtb);

    // attention: 144 chunks/head (128-q-row tiles, 8-k-tile chunks)
    attn_partial<<<dim3(144, N_HEADS), 256, 0, stream>>>(qkv, Vtb, part);
    attn_merge<<<dim3(T_SEQ / 128, N_HEADS), 256, 0, stream>>>(part, ctx);

    // Wo: [T,768] @ [768,768] + bo + x
    mfma_gemm<64, 64, 2, 2, 2, 2, 0><<<dim3(D_MODEL / 64, T_SEQ / 64), 256, 0, stream>>>(
        ctx, Wo_t, bo, x, x2, nullptr, T_SEQ, D_MODEL, D_MODEL);

    ln_kernel<<<T_SEQ, 256, 0, stream>>>(x2, g2, s2, h2);

    // FF1+FF2 fused with SwiGLU epilogue: 128x128 tile
    mfma_gemm<128, 128, 2, 2, 4, 4, 1><<<dim3(AG_LD / 128, T_SEQ / 128), 256, 0, stream>>>(
        h2, W12_t, b12, nullptr, nullptr, u, T_SEQ, AG_LD, D_MODEL);

    // FF3: [T,3072] @ [3072,768] + b3 + x2
    mfma_gemm<64, 64, 2, 2, 2, 2, 0><<<dim3(D_MODEL / 64, T_SEQ / 64), 256, 0, stream>>>(
        u, W3_t, b3, x2, out, nullptr, T_SEQ, D_MODEL, FF_DIM);
}

// Round 13
// 412.807 us; speedup vs baseline: 1.0302x; 1.0302x over previous
//
#include <hip/hip_runtime.h>

#define T_SEQ 4096
#define D_MODEL 768
#define N_HEADS 12
#define HEAD_DIM 64
#define FF_DIM 3072
#define QKV_LD 2304    // 3*D_MODEL
#define AG_LD  6144    // 2*FF_DIM
#define KCHUNK 8       // k-tiles (of 64 keys) per attention block
#define PSH 8448       // shorts per partial: 128*64 bf16 O + 128 fp32 l (256 shorts)

typedef __bf16 bf16x8 __attribute__((ext_vector_type(8)));
typedef float  f32x4  __attribute__((ext_vector_type(4)));

__device__ __forceinline__ unsigned short f2bf(float f) {
    unsigned int u = __float_as_uint(f);
    u += 0x7FFFu + ((u >> 16) & 1u);
    return (unsigned short)(u >> 16);
}
__device__ __forceinline__ float bf2f(unsigned short s) {
    return __uint_as_float(((unsigned int)s) << 16);
}
__device__ __forceinline__ f32x4 mfma16(bf16x8 a, bf16x8 b, f32x4 c) {
    return __builtin_amdgcn_mfma_f32_16x16x32_bf16(a, b, c, 0, 0, 0);
}
// async global->LDS, 16B per lane; LDS dest = wave-uniform base + lane*16
__device__ __forceinline__ void gload_lds16(const unsigned short* g, unsigned short* l) {
    __builtin_amdgcn_global_load_lds(
        (const __attribute__((address_space(1))) unsigned int*)g,
        (__attribute__((address_space(3))) unsigned int*)l,
        16, 0, 0);
}

// ---------------------------------------------------------------------------
// Fused prep: weight transposes (jobs 0..9215) + interleaved bias pack
// (9216..9227) + LayerNorm1 (9228..13323). One launch, independent jobs.
// ---------------------------------------------------------------------------
__global__ __launch_bounds__(256) void prep_fused(const float* __restrict__ Wq,
                                                  const float* __restrict__ Wk,
                                                  const float* __restrict__ Wv,
                                                  const float* __restrict__ Wo,
                                                  const float* __restrict__ w1,
                                                  const float* __restrict__ w2,
                                                  const float* __restrict__ w3,
                                                  unsigned short* __restrict__ Wqkv_t,
                                                  unsigned short* __restrict__ Wo_t,
                                                  unsigned short* __restrict__ W12_t,
                                                  unsigned short* __restrict__ W3_t,
                                                  const float* __restrict__ b1,
                                                  const float* __restrict__ b2,
                                                  float* __restrict__ b12,
                                                  const float* __restrict__ x,
                                                  const float* __restrict__ g1,
                                                  const float* __restrict__ s1,
                                                  unsigned short* __restrict__ hout) {
    __shared__ float tile[32][33];
    __shared__ float red[4];
    __shared__ float mv[2];
    const int b = blockIdx.x;
    const int tid = threadIdx.x;

    if (b >= 9228) {                      // --- LayerNorm1 on row (b-9228) ---
        const int row = b - 9228;
        const float* xr = x + (size_t)row * D_MODEL;
        unsigned short* orow = hout + (size_t)row * D_MODEL;
        float v0 = xr[tid], v1 = xr[tid + 256], v2 = xr[tid + 512];
        float sum = v0 + v1 + v2;
        const int lane = tid & 63, wv = tid >> 6;
        #pragma unroll
        for (int off = 32; off > 0; off >>= 1) sum += __shfl_down(sum, off, 64);
        if (lane == 0) red[wv] = sum;
        __syncthreads();
        if (tid == 0) mv[0] = (red[0] + red[1] + red[2] + red[3]) * (1.0f / D_MODEL);
        __syncthreads();
        const float mean = mv[0];
        float d0 = v0 - mean, d1 = v1 - mean, d2 = v2 - mean;
        float sq = d0 * d0 + d1 * d1 + d2 * d2;
        #pragma unroll
        for (int off = 32; off > 0; off >>= 1) sq += __shfl_down(sq, off, 64);
        if (lane == 0) red[wv] = sq;
        __syncthreads();
        if (tid == 0) mv[1] = (red[0] + red[1] + red[2] + red[3]) * (1.0f / D_MODEL);
        __syncthreads();
        const float rs = rsqrtf(mv[1] + 1e-5f);
        orow[tid]       = f2bf(g1[tid]       * d0 * rs + s1[tid]);
        orow[tid + 256] = f2bf(g1[tid + 256] * d1 * rs + s1[tid + 256]);
        orow[tid + 512] = f2bf(g1[tid + 512] * d2 * rs + s1[tid + 512]);
        return;
    }
    if (b >= 9216) {                      // --- bias pack ---
        const int n = (b - 9216) * 256 + tid;
        if (n < FF_DIM) {
            b12[(n >> 4) * 32 + (n & 15)] = b1[n];
            b12[(n >> 4) * 32 + 16 + (n & 15)] = b2[n];
        }
        return;
    }

    // --- weight transpose jobs ---
    const float* W; unsigned short* Wt;
    int K, N, off, ilv, bx, by;
    if (b < 2304) {                       // jobs 0-3: 576 blocks each (24x24)
        const int j = b / 576, lb = b % 576;
        bx = lb % 24; by = lb / 24;
        K = 768; N = 768; ilv = 0;
        if (j == 0)      { W = Wq; Wt = Wqkv_t; off = 0; }
        else if (j == 1) { W = Wk; Wt = Wqkv_t; off = 768; }
        else if (j == 2) { W = Wv; Wt = Wqkv_t; off = 1536; }
        else             { W = Wo; Wt = Wo_t;   off = 0; }
    } else if (b < 6912) {                // jobs 4-5: 2304 blocks each (96x24)
        const int j = (b - 2304) / 2304, lb = (b - 2304) % 2304;
        bx = lb % 96; by = lb / 96;
        K = 768; N = 3072; ilv = 1;
        W = j ? w2 : w1; Wt = W12_t; off = j ? 16 : 0;
    } else {                              // job 6: 2304 blocks (24x96)
        const int lb = b - 6912;
        bx = lb % 24; by = lb / 24;
        K = 3072; N = 768; ilv = 0;
        W = w3; Wt = W3_t; off = 0;
    }

    const int tx = tid & 31, ty = tid >> 5;  // 32 x 8
    const int n0 = bx * 32, k0 = by * 32;
    #pragma unroll
    for (int s = 0; s < 32; s += 8)
        tile[ty + s][tx] = W[(size_t)(k0 + ty + s) * N + n0 + tx];
    __syncthreads();
    #pragma unroll
    for (int s = 0; s < 32; s += 8) {
        const int nn = n0 + ty + s;
        const int R = ilv ? ((nn >> 4) * 32 + off + (nn & 15)) : (off + nn);
        Wt[(size_t)R * K + k0 + tx] = f2bf(tile[tx][ty + s]);
    }
}

// ---------------------------------------------------------------------------
// LayerNorm (fp32 in, bf16 out) — used for LN2
// ---------------------------------------------------------------------------
__global__ __launch_bounds__(256) void ln_kernel(const float* __restrict__ x,
                                                 const float* __restrict__ g,
                                                 const float* __restrict__ b,
                                                 unsigned short* __restrict__ o) {
    const int row = blockIdx.x;
    const float* xr = x + (size_t)row * D_MODEL;
    unsigned short* orow = o + (size_t)row * D_MODEL;
    const int tid = threadIdx.x;

    float v0 = xr[tid], v1 = xr[tid + 256], v2 = xr[tid + 512];
    float sum = v0 + v1 + v2;

    __shared__ float red[4];
    __shared__ float mv[2];
    const int lane = tid & 63, wv = tid >> 6;

    #pragma unroll
    for (int off = 32; off > 0; off >>= 1) sum += __shfl_down(sum, off, 64);
    if (lane == 0) red[wv] = sum;
    __syncthreads();
    if (tid == 0) mv[0] = (red[0] + red[1] + red[2] + red[3]) * (1.0f / D_MODEL);
    __syncthreads();
    const float mean = mv[0];

    float d0 = v0 - mean, d1 = v1 - mean, d2 = v2 - mean;
    float sq = d0 * d0 + d1 * d1 + d2 * d2;
    #pragma unroll
    for (int off = 32; off > 0; off >>= 1) sq += __shfl_down(sq, off, 64);
    if (lane == 0) red[wv] = sq;
    __syncthreads();
    if (tid == 0) mv[1] = (red[0] + red[1] + red[2] + red[3]) * (1.0f / D_MODEL);
    __syncthreads();
    const float rs = rsqrtf(mv[1] + 1e-5f);

    orow[tid]       = f2bf(g[tid]       * d0 * rs + b[tid]);
    orow[tid + 256] = f2bf(g[tid + 256] * d1 * rs + b[tid + 256]);
    orow[tid + 512] = f2bf(g[tid + 512] * d2 * rs + b[tid + 512]);
}

// ---------------------------------------------------------------------------
// bf16 MFMA GEMM, templated tile. BM=WY*MI*16, BN=WX*NI*16, BK=32, 256 thr,
// async global_load_lds staging, double-buffered, one barrier per iter.
// EPI=0: C = acc + bias + res -> Cf (fp32) or Cb (bf16), pitch N.
// EPI=1: SwiGLU epilogue on 16-col-interleaved B -> Cb, pitch N/2.
// EPI=2: QKV epilogue — Q/K blocks (bn<1536) write Cb; V blocks (bn>=1536)
//        LDS-transpose their tile and write Vt (= (ushort*)Cf) with the
//        kl(s) = (s&3)*16 + (s>>2) per-64 key permutation (matches P layout).
// ---------------------------------------------------------------------------
template<int BM, int BN, int WY, int WX, int MI, int NI, int EPI>
__global__ __launch_bounds__(256) void mfma_gemm(const unsigned short* __restrict__ A,
                                                 const unsigned short* __restrict__ Bt,
                                                 const float* __restrict__ bias,
                                                 const float* __restrict__ res,
                                                 float* __restrict__ Cf,
                                                 unsigned short* __restrict__ Cb,
                                                 int M, int N, int K) {
    constexpr int CA = BM * 4;
    constexpr int CT = BM * 4 + BN * 4;
    constexpr int SA = CA / 256;
    constexpr int ST = CT / 256;
    __shared__ unsigned short S[2][CT * 8];

    const int t = threadIdx.x;
    const int bn = blockIdx.x * BN;
    const int bm = blockIdx.y * BM;
    const int w = t >> 6, lane = t & 63;
    const int wy = w / WX, wx = w % WX;
    const int quad = lane >> 4, r = lane & 15;
    const int rc = lane & 15, kq = (lane >> 4) & 3;

    const unsigned short* gp[ST];
    #pragma unroll
    for (int s = 0; s < ST; ++s) {
        if (s < SA) gp[s] = A  + (size_t)(bm + (s * 4 + w) * 16 + rc) * K + kq * 8;
        else        gp[s] = Bt + (size_t)(bn + ((s - SA) * 4 + w) * 16 + rc) * K + kq * 8;
    }

    f32x4 acc[MI][NI];
    const f32x4 fz = {0.f, 0.f, 0.f, 0.f};
    #pragma unroll
    for (int i = 0; i < MI; ++i)
        #pragma unroll
        for (int j = 0; j < NI; ++j) acc[i][j] = fz;

    #pragma unroll
    for (int s = 0; s < ST; ++s)
        gload_lds16(gp[s], &S[0][(s * 256 + w * 64) * 8]);

    const int niter = K >> 5;
    for (int it = 0; it < niter; ++it) {
        const int buf = it & 1;
        __syncthreads();
        if (it + 1 < niter) {
            const int ko = (it + 1) * 32;
            #pragma unroll
            for (int s = 0; s < ST; ++s)
                gload_lds16(gp[s] + ko, &S[buf ^ 1][(s * 256 + w * 64) * 8]);
        }

        bf16x8 af[MI], bfr[NI];
        #pragma unroll
        for (int mi = 0; mi < MI; ++mi)
            af[mi] = *(const bf16x8*)(&S[buf][((wy * MI + mi) * 64 + lane) * 8]);
        #pragma unroll
        for (int ni = 0; ni < NI; ++ni)
            bfr[ni] = *(const bf16x8*)(&S[buf][(CA + (wx * NI + ni) * 64 + lane) * 8]);
        #pragma unroll
        for (int mi = 0; mi < MI; ++mi)
            #pragma unroll
            for (int ni = 0; ni < NI; ++ni)
                acc[mi][ni] = mfma16(af[mi], bfr[ni], acc[mi][ni]);
    }

    float bv[NI];
    #pragma unroll
    for (int ni = 0; ni < NI; ++ni)
        bv[ni] = bias ? bias[bn + (wx * NI + ni) * 16 + r] : 0.0f;

    if (EPI == 0) {
        #pragma unroll
        for (int mi = 0; mi < MI; ++mi) {
            #pragma unroll
            for (int i = 0; i < 4; ++i) {
                const int m = bm + (wy * MI + mi) * 16 + quad * 4 + i;
                #pragma unroll
                for (int ni = 0; ni < NI; ++ni) {
                    const int n = bn + (wx * NI + ni) * 16 + r;
                    float v = acc[mi][ni][i] + bv[ni];
                    if (res) v += res[(size_t)m * N + n];
                    if (Cf) Cf[(size_t)m * N + n] = v;
                    else    Cb[(size_t)m * N + n] = f2bf(v);
                }
            }
        }
    } else if (EPI == 1) {
        #pragma unroll
        for (int mi = 0; mi < MI; ++mi) {
            #pragma unroll
            for (int i = 0; i < 4; ++i) {
                const int m = bm + (wy * MI + mi) * 16 + quad * 4 + i;
                #pragma unroll
                for (int p = 0; p < NI / 2; ++p) {
                    float a = acc[mi][2 * p][i] + bv[2 * p];
                    float g = acc[mi][2 * p + 1][i] + bv[2 * p + 1];
                    float uu = a / (1.0f + __expf(-a)) * g;
                    const int n = (bn >> 1) + wx * (NI / 2) * 16 + p * 16 + r;
                    Cb[(size_t)m * (N >> 1) + n] = f2bf(uu);
                }
            }
        }
    } else {  // EPI == 2: QKV with fused V-transpose
        if (bn < 2 * D_MODEL) {
            #pragma unroll
            for (int mi = 0; mi < MI; ++mi) {
                #pragma unroll
                for (int i = 0; i < 4; ++i) {
                    const int m = bm + (wy * MI + mi) * 16 + quad * 4 + i;
                    #pragma unroll
                    for (int ni = 0; ni < NI; ++ni) {
                        const int n = bn + (wx * NI + ni) * 16 + r;
                        Cb[(size_t)m * N + n] = f2bf(acc[mi][ni][i]);
                    }
                }
            }
        } else {
            // V block: transpose 128x128 tile through LDS (two 64-row passes),
            // write Vt[feature][time] with per-64 key permutation kl(s).
            unsigned short* Vt = (unsigned short*)Cf;
            unsigned short* TB = &S[0][0];           // 16384 shorts avail, need 64*132=8448
            const int vc0 = bn - 2 * D_MODEL;
            #pragma unroll
            for (int g = 0; g < 2; ++g) {
                __syncthreads();                     // K-loop reads / prev pass reads done
                if (wy == g) {
                    #pragma unroll
                    for (int mi = 0; mi < MI; ++mi)
                        #pragma unroll
                        for (int i = 0; i < 4; ++i)
                            #pragma unroll
                            for (int ni = 0; ni < NI; ++ni)
                                TB[(mi * 16 + quad * 4 + i) * 132 + wx * 64 + ni * 16 + r] =
                                    f2bf(acc[mi][ni][i]);
                }
                __syncthreads();
                const int c = t >> 1, s0 = (t & 1) * 32;
                unsigned short ob[32];
                #pragma unroll
                for (int j = 0; j < 32; ++j) {
                    const int s = s0 + j;
                    ob[j] = TB[((s & 3) * 16 + (s >> 2)) * 132 + c];
                }
                unsigned short* dst = Vt + (size_t)(vc0 + c) * T_SEQ + bm + g * 64 + s0;
                #pragma unroll
                for (int j = 0; j < 32; j += 8)
                    *(uint4*)(dst + j) = *(uint4*)(ob + j);
            }
        }
    }
}

// ---------------------------------------------------------------------------
// Softmax step, 2 M-fragments (32 q-rows/wave), fixed-max: p = exp(s),
// masked -> 0. b64 P writes with XOR bank swizzle; per-mi 1024-short region.
// V staged with matching key permutation (QKV EPI=2 epilogue).
// ---------------------------------------------------------------------------
template <bool DIAG>
__device__ __forceinline__ void softmax_step2(const f32x4 sacc[2][4],
                                              unsigned short* __restrict__ Pw,
                                              int k0, int qg0, int r, int quad) {
    const int rp = r >> 1;
    const int cbase = (r >> 3) * 64 + ((r >> 1) & 3) * 16;
    #pragma unroll
    for (int mi = 0; mi < 2; ++mi) {
        unsigned short* Pm = Pw + mi * 1024;
        #pragma unroll
        for (int i = 0; i < 4; ++i) {
            unsigned int pk[2];
            #pragma unroll
            for (int ni = 0; ni < 4; ++ni) {
                float p = __expf(sacc[mi][ni][i]);
                if (DIAG) { if (k0 + ni * 16 + r > qg0 + mi * 16 + i) p = 0.0f; }
                const unsigned int pb = (__float_as_uint(p) + 0x8000u) >> 16;
                if (ni & 1) pk[ni >> 1] |= pb << 16;
                else        pk[ni >> 1] = pb;
            }
            const int rrp = (quad * 4 + i) ^ rp;
            uint2 wv; wv.x = pk[0]; wv.y = pk[1];
            *(uint2*)(&Pm[(cbase + rrp) * 8 + 4 * (r & 1)]) = wv;
        }
    }
}

// ---------------------------------------------------------------------------
// Flash attention partial: 128 q-rows per block (wave = 32 rows), K-split
// into chunks of <=8 k-tiles. Partial O in bf16 (thread-contiguous r*4+nd
// micro-layout -> coalesced 8B stores) + l in fp32, to workspace.
// ---------------------------------------------------------------------------
__global__ __launch_bounds__(256) void attn_partial(const unsigned short* __restrict__ qkv,
                                                    const unsigned short* __restrict__ Vt,
                                                    unsigned short* __restrict__ part) {
    const int h = blockIdx.y;
    int b = (int)blockIdx.x, qt = 31, ci = 0;
    for (int q = 31; q >= 0; --q) {          // longest q-tiles first
        const int nc = (2 * q + 9) >> 3;     // ceil((2q+2)/8)
        if (b < nc) { qt = q; ci = b; break; }
        b -= nc;
    }
    const int q0 = qt * 128;
    const int kb = ci * KCHUNK;
    const int nt = min(KCHUNK, 2 * qt + 2 - kb);

    const int t = threadIdx.x;
    const int w = t >> 6, lane = t & 63;
    const int quad = lane >> 4, r = lane & 15;

    __shared__ unsigned short Ks[2][4096];
    __shared__ unsigned short Vs[2][4096];
    __shared__ unsigned short Ps[4][2048];

    // Q fragments (scale 1/8 folded in): rows q0 + w*32 + mi*16 + r
    bf16x8 aq[2][2];   // [ks][mi]
    #pragma unroll
    for (int mi = 0; mi < 2; ++mi) {
        const unsigned short* qp = qkv + (size_t)(q0 + w * 32 + mi * 16 + r) * QKV_LD + h * 64 + quad * 8;
        uint4 q0v = *(const uint4*)(qp);
        uint4 q1v = *(const uint4*)(qp + 32);
        const unsigned short* p0 = (const unsigned short*)&q0v;
        const unsigned short* p1 = (const unsigned short*)&q1v;
        #pragma unroll
        for (int j = 0; j < 8; ++j) {
            aq[0][mi][j] = (__bf16)(bf2f(p0[j]) * 0.125f);
            aq[1][mi][j] = (__bf16)(bf2f(p1[j]) * 0.125f);
        }
    }

    bf16x8 ones;
    #pragma unroll
    for (int j = 0; j < 8; ++j) ones[j] = (__bf16)1.0f;

    // per-lane staging sources (chunk c = s*256 + w*64 + lane), offset by kb
    const int rc = lane & 15, qc = (lane >> 4) & 3;
    const unsigned short* kg0 = qkv + (size_t)(kb * 64 + w * 16 + rc) * QKV_LD + D_MODEL + h * 64 + qc * 8;
    const unsigned short* kg1 = kg0 + 32;
    const unsigned short* vg0 = Vt + (size_t)(h * 64 + w * 16 + rc) * T_SEQ + kb * 64 + qc * 8;
    const unsigned short* vg1 = vg0 + 32;
    const int l0 = (w * 64) * 8, l1 = (256 + w * 64) * 8;

    const f32x4 fz = {0.f, 0.f, 0.f, 0.f};
    f32x4 acc_o[2][4] = {{fz, fz, fz, fz}, {fz, fz, fz, fz}};
    f32x4 acc_l[2] = {fz, fz};
    const int qg0 = q0 + w * 32 + quad * 4;

    gload_lds16(kg0, &Ks[0][l0]);
    gload_lds16(kg1, &Ks[0][l1]);
    gload_lds16(vg0, &Vs[0][l0]);
    gload_lds16(vg1, &Vs[0][l1]);

    for (int lt = 0; lt < nt; ++lt) {
        const int kt = kb + lt;
        const int buf = lt & 1;
        __syncthreads();
        if (lt + 1 < nt) {
            const size_t kofs = (size_t)(lt + 1) * 64;
            gload_lds16(kg0 + kofs * QKV_LD, &Ks[buf ^ 1][l0]);
            gload_lds16(kg1 + kofs * QKV_LD, &Ks[buf ^ 1][l1]);
            gload_lds16(vg0 + kofs, &Vs[buf ^ 1][l0]);
            gload_lds16(vg1 + kofs, &Vs[buf ^ 1][l1]);
        }

        // S = (Q/8) @ K^T : 16 MFMA off 8 shared K reads
        f32x4 sacc[2][4] = {{fz, fz, fz, fz}, {fz, fz, fz, fz}};
        #pragma unroll
        for (int ks = 0; ks < 2; ++ks)
            #pragma unroll
            for (int ni = 0; ni < 4; ++ni) {
                bf16x8 bk = *(const bf16x8*)(&Ks[buf][((ks * 4 + ni) * 64 + lane) * 8]);
                sacc[0][ni] = mfma16(aq[ks][0], bk, sacc[0][ni]);
                sacc[1][ni] = mfma16(aq[ks][1], bk, sacc[1][ni]);
            }

        const int k0 = kt * 64;
        if (kt >= 2 * qt)
            softmax_step2<true >(sacc, Ps[w], k0, qg0, r, quad);
        else
            softmax_step2<false>(sacc, Ps[w], k0, qg0, r, quad);

        // O += P @ V ; l += P @ 1 : 20 MFMA off 8 shared V reads
        const int kqr = lane >> 4, rrr = lane & 15;
        #pragma unroll
        for (int ks = 0; ks < 2; ++ks) {
            const int pc = ks * 64 + kqr * 16 + (rrr ^ (ks * 4 + kqr));
            bf16x8 ap0 = *(const bf16x8*)(&Ps[w][pc * 8]);
            bf16x8 ap1 = *(const bf16x8*)(&Ps[w][1024 + pc * 8]);
            #pragma unroll
            for (int nd = 0; nd < 4; ++nd) {
                bf16x8 bv = *(const bf16x8*)(&Vs[buf][((ks * 4 + nd) * 64 + lane) * 8]);
                acc_o[0][nd] = mfma16(ap0, bv, acc_o[0][nd]);
                acc_o[1][nd] = mfma16(ap1, bv, acc_o[1][nd]);
            }
            acc_l[0] = mfma16(ap0, ones, acc_l[0]);
            acc_l[1] = mfma16(ap1, ones, acc_l[1]);
        }
    }

    // write bf16 partial O (micro-layout col' = r*4 + nd) + fp32 l
    unsigned short* pb = part + ((size_t)(qt * N_HEADS + h) * KCHUNK + ci) * PSH;
    float* pl = (float*)(pb + 8192);
    #pragma unroll
    for (int mi = 0; mi < 2; ++mi) {
        #pragma unroll
        for (int i = 0; i < 4; ++i) {
            const int row = w * 32 + mi * 16 + quad * 4 + i;
            unsigned short ob[4];
            #pragma unroll
            for (int nd = 0; nd < 4; ++nd) ob[nd] = f2bf(acc_o[mi][nd][i]);
            *(uint2*)(pb + row * 64 + r * 4) = *(uint2*)ob;
            if (r == 0) pl[row] = acc_l[mi][i];
        }
    }
}

// ---------------------------------------------------------------------------
// Merge partials (bf16 O, fp32 l): ctx = (sum O) / (sum l). grid (32, 12).
// thread -> row = t>>1, col'-half = (t&1)*32. Unpermute col' = q*4+p ->
// col = p*16 + (t&1)*8 + q on the ctx write (4 uint4 runs).
// ---------------------------------------------------------------------------
__global__ __launch_bounds__(256) void attn_merge(const unsigned short* __restrict__ part,
                                                  unsigned short* __restrict__ ctx) {
    const int qt = blockIdx.x, h = blockIdx.y;
    const int nc = (2 * qt + 9) >> 3;
    const int t = threadIdx.x;
    const int row = t >> 1, half = t & 1, cp0 = half * 32;

    float o[32];
    #pragma unroll
    for (int j = 0; j < 32; ++j) o[j] = 0.0f;
    float l = 0.0f;

    for (int ci = 0; ci < nc; ++ci) {
        const unsigned short* pb = part + ((size_t)(qt * N_HEADS + h) * KCHUNK + ci) * PSH;
        l += ((const float*)(pb + 8192))[row];
        #pragma unroll
        for (int j0 = 0; j0 < 32; j0 += 8) {
            uint4 v = *(const uint4*)(pb + row * 64 + cp0 + j0);
            const unsigned short* pv = (const unsigned short*)&v;
            #pragma unroll
            for (int j = 0; j < 8; ++j) o[j0 + j] += bf2f(pv[j]);
        }
    }
    const float inv = 1.0f / l;
    unsigned short* base = ctx + (size_t)(qt * 128 + row) * D_MODEL + h * 64;
    #pragma unroll
    for (int p = 0; p < 4; ++p) {
        unsigned short ob[8];
        #pragma unroll
        for (int q = 0; q < 8; ++q) ob[q] = f2bf(o[q * 4 + p] * inv);
        *(uint4*)(base + p * 16 + half * 8) = *(uint4*)ob;
    }
}

// ---------------------------------------------------------------------------
// launch
// ---------------------------------------------------------------------------
extern "C" void kernel_launch(void* const* d_in, const int* in_sizes, int n_in,
                              void* d_out, int out_size, void* d_ws, size_t ws_size,
                              hipStream_t stream) {
    const float* x  = (const float*)d_in[0];
    const float* Wq = (const float*)d_in[1];
    const float* Wk = (const float*)d_in[2];
    const float* Wv = (const float*)d_in[3];
    const float* Wo = (const float*)d_in[4];
    const float* bo = (const float*)d_in[5];
    const float* w1 = (const float*)d_in[6];
    const float* b1 = (const float*)d_in[7];
    const float* w2 = (const float*)d_in[8];
    const float* b2 = (const float*)d_in[9];
    const float* w3 = (const float*)d_in[10];
    const float* b3 = (const float*)d_in[11];
    const float* g1 = (const float*)d_in[12];
    const float* s1 = (const float*)d_in[13];
    const float* g2 = (const float*)d_in[14];
    const float* s2 = (const float*)d_in[15];
    float* out = (float*)d_out;

    const size_t TD = (size_t)T_SEQ * D_MODEL;

    char* p = (char*)d_ws;
    auto alloc = [&](size_t bytes) { char* r = p; p += (bytes + 255) & ~(size_t)255; return r; };
    // persistent region (live across attention)
    unsigned short* qkv    = (unsigned short*)alloc((size_t)T_SEQ * QKV_LD * 2);
    unsigned short* Vtb    = (unsigned short*)alloc((size_t)D_MODEL * T_SEQ * 2);
    unsigned short* ctx    = (unsigned short*)alloc(TD * 2);
    unsigned short* Wqkv_t = (unsigned short*)alloc((size_t)QKV_LD * D_MODEL * 2);
    unsigned short* Wo_t   = (unsigned short*)alloc((size_t)D_MODEL * D_MODEL * 2);
    unsigned short* W12_t  = (unsigned short*)alloc((size_t)AG_LD * D_MODEL * 2);
    unsigned short* W3_t   = (unsigned short*)alloc((size_t)D_MODEL * FF_DIM * 2);
    float*          b12    = (float*)alloc((size_t)AG_LD * 4);
    // overlay region: part (attn_partial->attn_merge) aliases {h, x2, h2, u},
    // lifetime-disjoint (h dead after QKV; x2/h2/u written only after merge).
    const size_t part_bytes = (size_t)32 * N_HEADS * KCHUNK * PSH * 2;   // 51.9 MB
    const size_t overlay_bytes = ((TD * 2 + 255) & ~(size_t)255) + ((TD * 4 + 255) & ~(size_t)255)
                               + ((TD * 2 + 255) & ~(size_t)255) + (size_t)T_SEQ * FF_DIM * 2;
    char* R = alloc(part_bytes > overlay_bytes ? part_bytes : overlay_bytes);
    unsigned short* part = (unsigned short*)R;
    unsigned short* h    = (unsigned short*)R;
    float*          x2   = (float*)(R + ((TD * 2 + 255) & ~(size_t)255));
    unsigned short* h2   = (unsigned short*)((char*)x2 + ((TD * 4 + 255) & ~(size_t)255));
    unsigned short* u    = (unsigned short*)((char*)h2 + ((TD * 2 + 255) & ~(size_t)255));

    // --- fused prep: weight transposes + bias pack + LN1 ---
    prep_fused<<<13324, 256, 0, stream>>>(Wq, Wk, Wv, Wo, w1, w2, w3,
                                          Wqkv_t, Wo_t, W12_t, W3_t,
                                          b1, b2, b12, x, g1, s1, h);

    // QKV: [T,768] @ [768,2304]; V blocks write Vtb transposed (EPI=2)
    mfma_gemm<128, 128, 2, 2, 4, 4, 2><<<dim3(QKV_LD / 128, T_SEQ / 128), 256, 0, stream>>>(
        h, Wqkv_t, nullptr, nullptr, (float*)Vtb, qkv, T_SEQ, QKV_LD, D_MODEL);

    // attention: 144 chunks/head (128-q-row tiles, 8-k-tile chunks)
    attn_partial<<<dim3(144, N_HEADS), 256, 0, stream>>>(qkv, Vtb, part);
    attn_merge<<<dim3(T_SEQ / 128, N_HEADS), 256, 0, stream>>>(part, ctx);

    // Wo: [T,768] @ [768,768] + bo + x
    mfma_gemm<64, 64, 2, 2, 2, 2, 0><<<dim3(D_MODEL / 64, T_SEQ / 64), 256, 0, stream>>>(
        ctx, Wo_t, bo, x, x2, nullptr, T_SEQ, D_MODEL, D_MODEL);

    ln_kernel<<<T_SEQ, 256, 0, stream>>>(x2, g2, s2, h2);

    // FF1+FF2 fused with SwiGLU epilogue: 128x128 tile
    mfma_gemm<128, 128, 2, 2, 4, 4, 1><<<dim3(AG_LD / 128, T_SEQ / 128), 256, 0, stream>>>(
        h2, W12_t, b12, nullptr, nullptr, u, T_SEQ, AG_LD, D_MODEL);

    // FF3: [T,3072] @ [3072,768] + b3 + x2
    mfma_gemm<64, 64, 2, 2, 2, 2, 0><<<dim3(D_MODEL / 64, T_SEQ / 64), 256, 0, stream>>>(
        u, W3_t, b3, x2, out, nullptr, T_SEQ, D_MODEL, FF_DIM);
}

// Round 14
// 412.766 us; speedup vs baseline: 1.0303x; 1.0001x over previous
//
#include <hip/hip_runtime.h>

#define T_SEQ 4096
#define D_MODEL 768
#define N_HEADS 12
#define HEAD_DIM 64
#define FF_DIM 3072
#define QKV_LD 2304    // 3*D_MODEL
#define AG_LD  6144    // 2*FF_DIM
#define KCHUNK 8       // k-tiles (of 64 keys) per attention block
#define PSH 8448       // shorts per partial: 128*64 bf16 O + 128 fp32 l

typedef __bf16 bf16x8 __attribute__((ext_vector_type(8)));
typedef float  f32x4  __attribute__((ext_vector_type(4)));

__device__ __forceinline__ unsigned short f2bf(float f) {
    unsigned int u = __float_as_uint(f);
    u += 0x7FFFu + ((u >> 16) & 1u);
    return (unsigned short)(u >> 16);
}
__device__ __forceinline__ float bf2f(unsigned short s) {
    return __uint_as_float(((unsigned int)s) << 16);
}
__device__ __forceinline__ f32x4 mfma16(bf16x8 a, bf16x8 b, f32x4 c) {
    return __builtin_amdgcn_mfma_f32_16x16x32_bf16(a, b, c, 0, 0, 0);
}
// async global->LDS, 16B per lane; LDS dest = wave-uniform base + lane*16
__device__ __forceinline__ void gload_lds16(const unsigned short* g, unsigned short* l) {
    __builtin_amdgcn_global_load_lds(
        (const __attribute__((address_space(1))) unsigned int*)g,
        (__attribute__((address_space(3))) unsigned int*)l,
        16, 0, 0);
}

// ---------------------------------------------------------------------------
// Fused prep: weight transposes (jobs 0..9215) + interleaved bias pack
// (9216..9227) + LayerNorm1 (9228..13323). One launch, independent jobs.
// ---------------------------------------------------------------------------
__global__ __launch_bounds__(256) void prep_fused(const float* __restrict__ Wq,
                                                  const float* __restrict__ Wk,
                                                  const float* __restrict__ Wv,
                                                  const float* __restrict__ Wo,
                                                  const float* __restrict__ w1,
                                                  const float* __restrict__ w2,
                                                  const float* __restrict__ w3,
                                                  unsigned short* __restrict__ Wqkv_t,
                                                  unsigned short* __restrict__ Wo_t,
                                                  unsigned short* __restrict__ W12_t,
                                                  unsigned short* __restrict__ W3_t,
                                                  const float* __restrict__ b1,
                                                  const float* __restrict__ b2,
                                                  float* __restrict__ b12,
                                                  const float* __restrict__ x,
                                                  const float* __restrict__ g1,
                                                  const float* __restrict__ s1,
                                                  unsigned short* __restrict__ hout) {
    __shared__ float tile[32][33];
    __shared__ float red[4];
    __shared__ float mv[2];
    const int b = blockIdx.x;
    const int tid = threadIdx.x;

    if (b >= 9228) {                      // --- LayerNorm1 on row (b-9228) ---
        const int row = b - 9228;
        const float* xr = x + (size_t)row * D_MODEL;
        unsigned short* orow = hout + (size_t)row * D_MODEL;
        float v0 = xr[tid], v1 = xr[tid + 256], v2 = xr[tid + 512];
        float sum = v0 + v1 + v2;
        const int lane = tid & 63, wv = tid >> 6;
        #pragma unroll
        for (int off = 32; off > 0; off >>= 1) sum += __shfl_down(sum, off, 64);
        if (lane == 0) red[wv] = sum;
        __syncthreads();
        if (tid == 0) mv[0] = (red[0] + red[1] + red[2] + red[3]) * (1.0f / D_MODEL);
        __syncthreads();
        const float mean = mv[0];
        float d0 = v0 - mean, d1 = v1 - mean, d2 = v2 - mean;
        float sq = d0 * d0 + d1 * d1 + d2 * d2;
        #pragma unroll
        for (int off = 32; off > 0; off >>= 1) sq += __shfl_down(sq, off, 64);
        if (lane == 0) red[wv] = sq;
        __syncthreads();
        if (tid == 0) mv[1] = (red[0] + red[1] + red[2] + red[3]) * (1.0f / D_MODEL);
        __syncthreads();
        const float rs = rsqrtf(mv[1] + 1e-5f);
        orow[tid]       = f2bf(g1[tid]       * d0 * rs + s1[tid]);
        orow[tid + 256] = f2bf(g1[tid + 256] * d1 * rs + s1[tid + 256]);
        orow[tid + 512] = f2bf(g1[tid + 512] * d2 * rs + s1[tid + 512]);
        return;
    }
    if (b >= 9216) {                      // --- bias pack ---
        const int n = (b - 9216) * 256 + tid;
        if (n < FF_DIM) {
            b12[(n >> 4) * 32 + (n & 15)] = b1[n];
            b12[(n >> 4) * 32 + 16 + (n & 15)] = b2[n];
        }
        return;
    }

    // --- weight transpose jobs ---
    const float* W; unsigned short* Wt;
    int K, N, off, ilv, bx, by;
    if (b < 2304) {                       // jobs 0-3: 576 blocks each (24x24)
        const int j = b / 576, lb = b % 576;
        bx = lb % 24; by = lb / 24;
        K = 768; N = 768; ilv = 0;
        if (j == 0)      { W = Wq; Wt = Wqkv_t; off = 0; }
        else if (j == 1) { W = Wk; Wt = Wqkv_t; off = 768; }
        else if (j == 2) { W = Wv; Wt = Wqkv_t; off = 1536; }
        else             { W = Wo; Wt = Wo_t;   off = 0; }
    } else if (b < 6912) {                // jobs 4-5: 2304 blocks each (96x24)
        const int j = (b - 2304) / 2304, lb = (b - 2304) % 2304;
        bx = lb % 96; by = lb / 96;
        K = 768; N = 3072; ilv = 1;
        W = j ? w2 : w1; Wt = W12_t; off = j ? 16 : 0;
    } else {                              // job 6: 2304 blocks (24x96)
        const int lb = b - 6912;
        bx = lb % 24; by = lb / 24;
        K = 3072; N = 768; ilv = 0;
        W = w3; Wt = W3_t; off = 0;
    }

    const int tx = tid & 31, ty = tid >> 5;  // 32 x 8
    const int n0 = bx * 32, k0 = by * 32;
    #pragma unroll
    for (int s = 0; s < 32; s += 8)
        tile[ty + s][tx] = W[(size_t)(k0 + ty + s) * N + n0 + tx];
    __syncthreads();
    #pragma unroll
    for (int s = 0; s < 32; s += 8) {
        const int nn = n0 + ty + s;
        const int R = ilv ? ((nn >> 4) * 32 + off + (nn & 15)) : (off + nn);
        Wt[(size_t)R * K + k0 + tx] = f2bf(tile[tx][ty + s]);
    }
}

// ---------------------------------------------------------------------------
// LayerNorm (fp32 in, bf16 out) — used for LN2
// ---------------------------------------------------------------------------
__global__ __launch_bounds__(256) void ln_kernel(const float* __restrict__ x,
                                                 const float* __restrict__ g,
                                                 const float* __restrict__ b,
                                                 unsigned short* __restrict__ o) {
    const int row = blockIdx.x;
    const float* xr = x + (size_t)row * D_MODEL;
    unsigned short* orow = o + (size_t)row * D_MODEL;
    const int tid = threadIdx.x;

    float v0 = xr[tid], v1 = xr[tid + 256], v2 = xr[tid + 512];
    float sum = v0 + v1 + v2;

    __shared__ float red[4];
    __shared__ float mv[2];
    const int lane = tid & 63, wv = tid >> 6;

    #pragma unroll
    for (int off = 32; off > 0; off >>= 1) sum += __shfl_down(sum, off, 64);
    if (lane == 0) red[wv] = sum;
    __syncthreads();
    if (tid == 0) mv[0] = (red[0] + red[1] + red[2] + red[3]) * (1.0f / D_MODEL);
    __syncthreads();
    const float mean = mv[0];

    float d0 = v0 - mean, d1 = v1 - mean, d2 = v2 - mean;
    float sq = d0 * d0 + d1 * d1 + d2 * d2;
    #pragma unroll
    for (int off = 32; off > 0; off >>= 1) sq += __shfl_down(sq, off, 64);
    if (lane == 0) red[wv] = sq;
    __syncthreads();
    if (tid == 0) mv[1] = (red[0] + red[1] + red[2] + red[3]) * (1.0f / D_MODEL);
    __syncthreads();
    const float rs = rsqrtf(mv[1] + 1e-5f);

    orow[tid]       = f2bf(g[tid]       * d0 * rs + b[tid]);
    orow[tid + 256] = f2bf(g[tid + 256] * d1 * rs + b[tid + 256]);
    orow[tid + 512] = f2bf(g[tid + 512] * d2 * rs + b[tid + 512]);
}

// ---------------------------------------------------------------------------
// bf16 MFMA GEMM, templated tile + BK. BM=WY*MI*16, BN=WX*NI*16, 256 thr,
// async global_load_lds staging, double-buffered, ONE barrier per BK-block.
// BK=64 halves barrier count vs BK=32 and doubles compute per barrier, so
// the vmcnt(0) drain at each barrier has >= load-latency of slack.
// Chunk layout per matrix: chunk = g*(16*KC) + kc*16 + rc holds
// X[g*16+rc][kc*8..+8], KC = BK/8.
// EPI=0: C = acc + bias + res -> Cf (fp32) or Cb (bf16), pitch N.
// EPI=1: SwiGLU epilogue on 16-col-interleaved B -> Cb, pitch N/2.
// EPI=2: QKV epilogue — Q/K blocks write Cb; V blocks (bn>=1536)
//        LDS-transpose their tile and write Vt (= (ushort*)Cf) with the
//        kl(s) = (s&3)*16 + (s>>2) per-64 key permutation.
// ---------------------------------------------------------------------------
template<int BM, int BN, int BK, int WY, int WX, int MI, int NI, int EPI>
__global__ __launch_bounds__(256) void mfma_gemm(const unsigned short* __restrict__ A,
                                                 const unsigned short* __restrict__ Bt,
                                                 const float* __restrict__ bias,
                                                 const float* __restrict__ res,
                                                 float* __restrict__ Cf,
                                                 unsigned short* __restrict__ Cb,
                                                 int M, int N, int K) {
    constexpr int KC = BK / 8;            // 16B chunks per row
    constexpr int KI = BK / 32;           // MFMA sub-iterations
    constexpr int CA = BM * KC;           // A chunks
    constexpr int CT = (BM + BN) * KC;    // total chunks
    constexpr int ST = CT / 256;          // DMA steps
    __shared__ unsigned short S[2][CT * 8];

    const int t = threadIdx.x;
    const int bn = blockIdx.x * BN;
    const int bm = blockIdx.y * BM;
    const int w = t >> 6, lane = t & 63;
    const int wy = w / WX, wx = w % WX;
    const int quad = lane >> 4, r = lane & 15;

    const unsigned short* gp[ST];
    #pragma unroll
    for (int s = 0; s < ST; ++s) {
        const int c = s * 256 + w * 64 + lane;
        const bool isA = c < CA;
        const int cm = isA ? c : c - CA;
        const int g = cm / (16 * KC);
        const int kc = (cm >> 4) % KC;
        const int rc = cm & 15;
        gp[s] = (isA ? A + (size_t)(bm + g * 16 + rc) * K
                     : Bt + (size_t)(bn + g * 16 + rc) * K) + kc * 8;
    }

    f32x4 acc[MI][NI];
    const f32x4 fz = {0.f, 0.f, 0.f, 0.f};
    #pragma unroll
    for (int i = 0; i < MI; ++i)
        #pragma unroll
        for (int j = 0; j < NI; ++j) acc[i][j] = fz;

    #pragma unroll
    for (int s = 0; s < ST; ++s)
        gload_lds16(gp[s], &S[0][(s * 256 + w * 64) * 8]);

    const int niter = K / BK;
    for (int it = 0; it < niter; ++it) {
        const int buf = it & 1;
        __syncthreads();            // drains vmcnt: buf's DMA complete; prior reads done
        if (it + 1 < niter) {
            const int ko = (it + 1) * BK;
            #pragma unroll
            for (int s = 0; s < ST; ++s)
                gload_lds16(gp[s] + ko, &S[buf ^ 1][(s * 256 + w * 64) * 8]);
        }

        #pragma unroll
        for (int kk = 0; kk < KI; ++kk) {
            bf16x8 af[MI], bfr[NI];
            #pragma unroll
            for (int mi = 0; mi < MI; ++mi)
                af[mi] = *(const bf16x8*)(&S[buf][(((wy * MI + mi) * KC + kk * 4 + quad) * 16 + r) * 8]);
            #pragma unroll
            for (int ni = 0; ni < NI; ++ni)
                bfr[ni] = *(const bf16x8*)(&S[buf][(CA + ((wx * NI + ni) * KC + kk * 4 + quad) * 16 + r) * 8]);
            #pragma unroll
            for (int mi = 0; mi < MI; ++mi)
                #pragma unroll
                for (int ni = 0; ni < NI; ++ni)
                    acc[mi][ni] = mfma16(af[mi], bfr[ni], acc[mi][ni]);
        }
    }

    float bv[NI];
    #pragma unroll
    for (int ni = 0; ni < NI; ++ni)
        bv[ni] = bias ? bias[bn + (wx * NI + ni) * 16 + r] : 0.0f;

    if (EPI == 0) {
        #pragma unroll
        for (int mi = 0; mi < MI; ++mi) {
            #pragma unroll
            for (int i = 0; i < 4; ++i) {
                const int m = bm + (wy * MI + mi) * 16 + quad * 4 + i;
                #pragma unroll
                for (int ni = 0; ni < NI; ++ni) {
                    const int n = bn + (wx * NI + ni) * 16 + r;
                    float v = acc[mi][ni][i] + bv[ni];
                    if (res) v += res[(size_t)m * N + n];
                    if (Cf) Cf[(size_t)m * N + n] = v;
                    else    Cb[(size_t)m * N + n] = f2bf(v);
                }
            }
        }
    } else if (EPI == 1) {
        #pragma unroll
        for (int mi = 0; mi < MI; ++mi) {
            #pragma unroll
            for (int i = 0; i < 4; ++i) {
                const int m = bm + (wy * MI + mi) * 16 + quad * 4 + i;
                #pragma unroll
                for (int p = 0; p < NI / 2; ++p) {
                    float a = acc[mi][2 * p][i] + bv[2 * p];
                    float g = acc[mi][2 * p + 1][i] + bv[2 * p + 1];
                    float uu = a / (1.0f + __expf(-a)) * g;
                    const int n = (bn >> 1) + wx * (NI / 2) * 16 + p * 16 + r;
                    Cb[(size_t)m * (N >> 1) + n] = f2bf(uu);
                }
            }
        }
    } else {  // EPI == 2: QKV with fused V-transpose
        if (bn < 2 * D_MODEL) {
            #pragma unroll
            for (int mi = 0; mi < MI; ++mi) {
                #pragma unroll
                for (int i = 0; i < 4; ++i) {
                    const int m = bm + (wy * MI + mi) * 16 + quad * 4 + i;
                    #pragma unroll
                    for (int ni = 0; ni < NI; ++ni) {
                        const int n = bn + (wx * NI + ni) * 16 + r;
                        Cb[(size_t)m * N + n] = f2bf(acc[mi][ni][i]);
                    }
                }
            }
        } else {
            // V block: transpose 128x128 tile through LDS (two 64-row passes),
            // write Vt[feature][time] with per-64 key permutation kl(s).
            unsigned short* Vt = (unsigned short*)Cf;
            unsigned short* TB = &S[0][0];           // need 64*132 = 8448 shorts
            const int vc0 = bn - 2 * D_MODEL;
            #pragma unroll
            for (int g = 0; g < 2; ++g) {
                __syncthreads();                     // K-loop / prev pass reads done
                if (wy == g) {
                    #pragma unroll
                    for (int mi = 0; mi < MI; ++mi)
                        #pragma unroll
                        for (int i = 0; i < 4; ++i)
                            #pragma unroll
                            for (int ni = 0; ni < NI; ++ni)
                                TB[(mi * 16 + quad * 4 + i) * 132 + wx * 64 + ni * 16 + r] =
                                    f2bf(acc[mi][ni][i]);
                }
                __syncthreads();
                const int c = t >> 1, s0 = (t & 1) * 32;
                unsigned short ob[32];
                #pragma unroll
                for (int j = 0; j < 32; ++j) {
                    const int s = s0 + j;
                    ob[j] = TB[((s & 3) * 16 + (s >> 2)) * 132 + c];
                }
                unsigned short* dst = Vt + (size_t)(vc0 + c) * T_SEQ + bm + g * 64 + s0;
                #pragma unroll
                for (int j = 0; j < 32; j += 8)
                    *(uint4*)(dst + j) = *(uint4*)(ob + j);
            }
        }
    }
}

// ---------------------------------------------------------------------------
// Softmax step, 2 M-fragments (32 q-rows/wave), fixed-max: p = exp(s),
// masked -> 0. b64 P writes with XOR bank swizzle; per-mi 1024-short region.
// V staged with matching key permutation (QKV EPI=2 epilogue).
// ---------------------------------------------------------------------------
template <bool DIAG>
__device__ __forceinline__ void softmax_step2(const f32x4 sacc[2][4],
                                              unsigned short* __restrict__ Pw,
                                              int k0, int qg0, int r, int quad) {
    const int rp = r >> 1;
    const int cbase = (r >> 3) * 64 + ((r >> 1) & 3) * 16;
    #pragma unroll
    for (int mi = 0; mi < 2; ++mi) {
        unsigned short* Pm = Pw + mi * 1024;
        #pragma unroll
        for (int i = 0; i < 4; ++i) {
            unsigned int pk[2];
            #pragma unroll
            for (int ni = 0; ni < 4; ++ni) {
                float p = __expf(sacc[mi][ni][i]);
                if (DIAG) { if (k0 + ni * 16 + r > qg0 + mi * 16 + i) p = 0.0f; }
                const unsigned int pb = (__float_as_uint(p) + 0x8000u) >> 16;
                if (ni & 1) pk[ni >> 1] |= pb << 16;
                else        pk[ni >> 1] = pb;
            }
            const int rrp = (quad * 4 + i) ^ rp;
            uint2 wv; wv.x = pk[0]; wv.y = pk[1];
            *(uint2*)(&Pm[(cbase + rrp) * 8 + 4 * (r & 1)]) = wv;
        }
    }
}

// ---------------------------------------------------------------------------
// Flash attention partial: 128 q-rows per block (wave = 32 rows), K-split
// into chunks of <=8 k-tiles. Partial O in bf16 (thread-contiguous r*4+nd
// micro-layout -> coalesced 8B stores) + l in fp32, to workspace.
// ---------------------------------------------------------------------------
__global__ __launch_bounds__(256) void attn_partial(const unsigned short* __restrict__ qkv,
                                                    const unsigned short* __restrict__ Vt,
                                                    unsigned short* __restrict__ part) {
    const int h = blockIdx.y;
    int b = (int)blockIdx.x, qt = 31, ci = 0;
    for (int q = 31; q >= 0; --q) {          // longest q-tiles first
        const int nc = (2 * q + 9) >> 3;     // ceil((2q+2)/8)
        if (b < nc) { qt = q; ci = b; break; }
        b -= nc;
    }
    const int q0 = qt * 128;
    const int kb = ci * KCHUNK;
    const int nt = min(KCHUNK, 2 * qt + 2 - kb);

    const int t = threadIdx.x;
    const int w = t >> 6, lane = t & 63;
    const int quad = lane >> 4, r = lane & 15;

    __shared__ unsigned short Ks[2][4096];
    __shared__ unsigned short Vs[2][4096];
    __shared__ unsigned short Ps[4][2048];

    // Q fragments (scale 1/8 folded in): rows q0 + w*32 + mi*16 + r
    bf16x8 aq[2][2];   // [ks][mi]
    #pragma unroll
    for (int mi = 0; mi < 2; ++mi) {
        const unsigned short* qp = qkv + (size_t)(q0 + w * 32 + mi * 16 + r) * QKV_LD + h * 64 + quad * 8;
        uint4 q0v = *(const uint4*)(qp);
        uint4 q1v = *(const uint4*)(qp + 32);
        const unsigned short* p0 = (const unsigned short*)&q0v;
        const unsigned short* p1 = (const unsigned short*)&q1v;
        #pragma unroll
        for (int j = 0; j < 8; ++j) {
            aq[0][mi][j] = (__bf16)(bf2f(p0[j]) * 0.125f);
            aq[1][mi][j] = (__bf16)(bf2f(p1[j]) * 0.125f);
        }
    }

    bf16x8 ones;
    #pragma unroll
    for (int j = 0; j < 8; ++j) ones[j] = (__bf16)1.0f;

    // per-lane staging sources (chunk c = s*256 + w*64 + lane), offset by kb
    const int rc = lane & 15, qc = (lane >> 4) & 3;
    const unsigned short* kg0 = qkv + (size_t)(kb * 64 + w * 16 + rc) * QKV_LD + D_MODEL + h * 64 + qc * 8;
    const unsigned short* kg1 = kg0 + 32;
    const unsigned short* vg0 = Vt + (size_t)(h * 64 + w * 16 + rc) * T_SEQ + kb * 64 + qc * 8;
    const unsigned short* vg1 = vg0 + 32;
    const int l0 = (w * 64) * 8, l1 = (256 + w * 64) * 8;

    const f32x4 fz = {0.f, 0.f, 0.f, 0.f};
    f32x4 acc_o[2][4] = {{fz, fz, fz, fz}, {fz, fz, fz, fz}};
    f32x4 acc_l[2] = {fz, fz};
    const int qg0 = q0 + w * 32 + quad * 4;

    gload_lds16(kg0, &Ks[0][l0]);
    gload_lds16(kg1, &Ks[0][l1]);
    gload_lds16(vg0, &Vs[0][l0]);
    gload_lds16(vg1, &Vs[0][l1]);

    for (int lt = 0; lt < nt; ++lt) {
        const int kt = kb + lt;
        const int buf = lt & 1;
        __syncthreads();
        if (lt + 1 < nt) {
            const size_t kofs = (size_t)(lt + 1) * 64;
            gload_lds16(kg0 + kofs * QKV_LD, &Ks[buf ^ 1][l0]);
            gload_lds16(kg1 + kofs * QKV_LD, &Ks[buf ^ 1][l1]);
            gload_lds16(vg0 + kofs, &Vs[buf ^ 1][l0]);
            gload_lds16(vg1 + kofs, &Vs[buf ^ 1][l1]);
        }

        // S = (Q/8) @ K^T : 16 MFMA off 8 shared K reads
        f32x4 sacc[2][4] = {{fz, fz, fz, fz}, {fz, fz, fz, fz}};
        #pragma unroll
        for (int ks = 0; ks < 2; ++ks)
            #pragma unroll
            for (int ni = 0; ni < 4; ++ni) {
                bf16x8 bk = *(const bf16x8*)(&Ks[buf][((ks * 4 + ni) * 64 + lane) * 8]);
                sacc[0][ni] = mfma16(aq[ks][0], bk, sacc[0][ni]);
                sacc[1][ni] = mfma16(aq[ks][1], bk, sacc[1][ni]);
            }

        const int k0 = kt * 64;
        if (kt >= 2 * qt)
            softmax_step2<true >(sacc, Ps[w], k0, qg0, r, quad);
        else
            softmax_step2<false>(sacc, Ps[w], k0, qg0, r, quad);

        // O += P @ V ; l += P @ 1 : 20 MFMA off 8 shared V reads
        const int kqr = lane >> 4, rrr = lane & 15;
        #pragma unroll
        for (int ks = 0; ks < 2; ++ks) {
            const int pc = ks * 64 + kqr * 16 + (rrr ^ (ks * 4 + kqr));
            bf16x8 ap0 = *(const bf16x8*)(&Ps[w][pc * 8]);
            bf16x8 ap1 = *(const bf16x8*)(&Ps[w][1024 + pc * 8]);
            #pragma unroll
            for (int nd = 0; nd < 4; ++nd) {
                bf16x8 bv = *(const bf16x8*)(&Vs[buf][((ks * 4 + nd) * 64 + lane) * 8]);
                acc_o[0][nd] = mfma16(ap0, bv, acc_o[0][nd]);
                acc_o[1][nd] = mfma16(ap1, bv, acc_o[1][nd]);
            }
            acc_l[0] = mfma16(ap0, ones, acc_l[0]);
            acc_l[1] = mfma16(ap1, ones, acc_l[1]);
        }
    }

    // write bf16 partial O (micro-layout col' = r*4 + nd) + fp32 l
    unsigned short* pb = part + ((size_t)(qt * N_HEADS + h) * KCHUNK + ci) * PSH;
    float* pl = (float*)(pb + 8192);
    #pragma unroll
    for (int mi = 0; mi < 2; ++mi) {
        #pragma unroll
        for (int i = 0; i < 4; ++i) {
            const int row = w * 32 + mi * 16 + quad * 4 + i;
            unsigned short ob[4];
            #pragma unroll
            for (int nd = 0; nd < 4; ++nd) ob[nd] = f2bf(acc_o[mi][nd][i]);
            *(uint2*)(pb + row * 64 + r * 4) = *(uint2*)ob;
            if (r == 0) pl[row] = acc_l[mi][i];
        }
    }
}

// ---------------------------------------------------------------------------
// Merge partials (bf16 O, fp32 l): ctx = (sum O) / (sum l). grid (32, 12).
// thread -> row = t>>1, col'-half = (t&1)*32. Unpermute col' = q*4+p ->
// col = p*16 + (t&1)*8 + q on the ctx write (4 uint4 runs).
// ---------------------------------------------------------------------------
__global__ __launch_bounds__(256) void attn_merge(const unsigned short* __restrict__ part,
                                                  unsigned short* __restrict__ ctx) {
    const int qt = blockIdx.x, h = blockIdx.y;
    const int nc = (2 * qt + 9) >> 3;
    const int t = threadIdx.x;
    const int row = t >> 1, half = t & 1, cp0 = half * 32;

    float o[32];
    #pragma unroll
    for (int j = 0; j < 32; ++j) o[j] = 0.0f;
    float l = 0.0f;

    for (int ci = 0; ci < nc; ++ci) {
        const unsigned short* pb = part + ((size_t)(qt * N_HEADS + h) * KCHUNK + ci) * PSH;
        l += ((const float*)(pb + 8192))[row];
        #pragma unroll
        for (int j0 = 0; j0 < 32; j0 += 8) {
            uint4 v = *(const uint4*)(pb + row * 64 + cp0 + j0);
            const unsigned short* pv = (const unsigned short*)&v;
            #pragma unroll
            for (int j = 0; j < 8; ++j) o[j0 + j] += bf2f(pv[j]);
        }
    }
    const float inv = 1.0f / l;
    unsigned short* base = ctx + (size_t)(qt * 128 + row) * D_MODEL + h * 64;
    #pragma unroll
    for (int p = 0; p < 4; ++p) {
        unsigned short ob[8];
        #pragma unroll
        for (int q = 0; q < 8; ++q) ob[q] = f2bf(o[q * 4 + p] * inv);
        *(uint4*)(base + p * 16 + half * 8) = *(uint4*)ob;
    }
}

// ---------------------------------------------------------------------------
// launch
// ---------------------------------------------------------------------------
extern "C" void kernel_launch(void* const* d_in, const int* in_sizes, int n_in,
                              void* d_out, int out_size, void* d_ws, size_t ws_size,
                              hipStream_t stream) {
    const float* x  = (const float*)d_in[0];
    const float* Wq = (const float*)d_in[1];
    const float* Wk = (const float*)d_in[2];
    const float* Wv = (const float*)d_in[3];
    const float* Wo = (const float*)d_in[4];
    const float* bo = (const float*)d_in[5];
    const float* w1 = (const float*)d_in[6];
    const float* b1 = (const float*)d_in[7];
    const float* w2 = (const float*)d_in[8];
    const float* b2 = (const float*)d_in[9];
    const float* w3 = (const float*)d_in[10];
    const float* b3 = (const float*)d_in[11];
    const float* g1 = (const float*)d_in[12];
    const float* s1 = (const float*)d_in[13];
    const float* g2 = (const float*)d_in[14];
    const float* s2 = (const float*)d_in[15];
    float* out = (float*)d_out;

    const size_t TD = (size_t)T_SEQ * D_MODEL;

    char* p = (char*)d_ws;
    auto alloc = [&](size_t bytes) { char* r = p; p += (bytes + 255) & ~(size_t)255; return r; };
    // persistent region (live across attention)
    unsigned short* qkv    = (unsigned short*)alloc((size_t)T_SEQ * QKV_LD * 2);
    unsigned short* Vtb    = (unsigned short*)alloc((size_t)D_MODEL * T_SEQ * 2);
    unsigned short* ctx    = (unsigned short*)alloc(TD * 2);
    unsigned short* Wqkv_t = (unsigned short*)alloc((size_t)QKV_LD * D_MODEL * 2);
    unsigned short* Wo_t   = (unsigned short*)alloc((size_t)D_MODEL * D_MODEL * 2);
    unsigned short* W12_t  = (unsigned short*)alloc((size_t)AG_LD * D_MODEL * 2);
    unsigned short* W3_t   = (unsigned short*)alloc((size_t)D_MODEL * FF_DIM * 2);
    float*          b12    = (float*)alloc((size_t)AG_LD * 4);
    // overlay region: part (attn_partial->attn_merge) aliases {h, x2, h2, u},
    // lifetime-disjoint (h dead after QKV; x2/h2/u written only after merge).
    const size_t part_bytes = (size_t)32 * N_HEADS * KCHUNK * PSH * 2;   // 51.9 MB
    const size_t overlay_bytes = ((TD * 2 + 255) & ~(size_t)255) + ((TD * 4 + 255) & ~(size_t)255)
                               + ((TD * 2 + 255) & ~(size_t)255) + (size_t)T_SEQ * FF_DIM * 2;
    char* R = alloc(part_bytes > overlay_bytes ? part_bytes : overlay_bytes);
    unsigned short* part = (unsigned short*)R;
    unsigned short* h    = (unsigned short*)R;
    float*          x2   = (float*)(R + ((TD * 2 + 255) & ~(size_t)255));
    unsigned short* h2   = (unsigned short*)((char*)x2 + ((TD * 4 + 255) & ~(size_t)255));
    unsigned short* u    = (unsigned short*)((char*)h2 + ((TD * 2 + 255) & ~(size_t)255));

    // --- fused prep: weight transposes + bias pack + LN1 ---
    prep_fused<<<13324, 256, 0, stream>>>(Wq, Wk, Wv, Wo, w1, w2, w3,
                                          Wqkv_t, Wo_t, W12_t, W3_t,
                                          b1, b2, b12, x, g1, s1, h);

    // QKV: [T,768] @ [768,2304]; V blocks write Vtb transposed (EPI=2), BK=64
    mfma_gemm<128, 128, 64, 2, 2, 4, 4, 2><<<dim3(QKV_LD / 128, T_SEQ / 128), 256, 0, stream>>>(
        h, Wqkv_t, nullptr, nullptr, (float*)Vtb, qkv, T_SEQ, QKV_LD, D_MODEL);

    // attention: 144 chunks/head (128-q-row tiles, 8-k-tile chunks)
    attn_partial<<<dim3(144, N_HEADS), 256, 0, stream>>>(qkv, Vtb, part);
    attn_merge<<<dim3(T_SEQ / 128, N_HEADS), 256, 0, stream>>>(part, ctx);

    // Wo: [T,768] @ [768,768] + bo + x, BK=64
    mfma_gemm<64, 64, 64, 2, 2, 2, 2, 0><<<dim3(D_MODEL / 64, T_SEQ / 64), 256, 0, stream>>>(
        ctx, Wo_t, bo, x, x2, nullptr, T_SEQ, D_MODEL, D_MODEL);

    ln_kernel<<<T_SEQ, 256, 0, stream>>>(x2, g2, s2, h2);

    // FF1+FF2 fused with SwiGLU epilogue: 128x128 tile, BK=64
    mfma_gemm<128, 128, 64, 2, 2, 4, 4, 1><<<dim3(AG_LD / 128, T_SEQ / 128), 256, 0, stream>>>(
        h2, W12_t, b12, nullptr, nullptr, u, T_SEQ, AG_LD, D_MODEL);

    // FF3: [T,3072] @ [3072,768] + b3 + x2, BK=64
    mfma_gemm<64, 64, 64, 2, 2, 2, 2, 0><<<dim3(D_MODEL / 64, T_SEQ / 64), 256, 0, stream>>>(
        u, W3_t, b3, x2, out, nullptr, T_SEQ, D_MODEL, FF_DIM);
}

// Round 15
// 354.351 us; speedup vs baseline: 1.2002x; 1.1649x over previous
//
#include <hip/hip_runtime.h>

#define T_SEQ 4096
#define D_MODEL 768
#define N_HEADS 12
#define HEAD_DIM 64
#define FF_DIM 3072
#define QKV_LD 2304    // 3*D_MODEL
#define AG_LD  6144    // 2*FF_DIM
#define KCHUNK 8       // k-tiles (of 64 keys) per attention block
#define PSH 8448       // shorts per partial: 128*64 bf16 O + 128 fp32 l

typedef __bf16 bf16x8 __attribute__((ext_vector_type(8)));
typedef float  f32x4  __attribute__((ext_vector_type(4)));

__device__ __forceinline__ unsigned short f2bf(float f) {
    unsigned int u = __float_as_uint(f);
    u += 0x7FFFu + ((u >> 16) & 1u);
    return (unsigned short)(u >> 16);
}
__device__ __forceinline__ float bf2f(unsigned short s) {
    return __uint_as_float(((unsigned int)s) << 16);
}
__device__ __forceinline__ f32x4 mfma16(bf16x8 a, bf16x8 b, f32x4 c) {
    return __builtin_amdgcn_mfma_f32_16x16x32_bf16(a, b, c, 0, 0, 0);
}
// async global->LDS, 16B per lane; LDS dest = wave-uniform base + lane*16
__device__ __forceinline__ void gload_lds16(const unsigned short* g, unsigned short* l) {
    __builtin_amdgcn_global_load_lds(
        (const __attribute__((address_space(1))) unsigned int*)g,
        (__attribute__((address_space(3))) unsigned int*)l,
        16, 0, 0);
}

// Packed activation index for BM=128, BK=64, K=768 consumers (QKV, FF12):
// element (m, k) -> tile(m>>7, k>>6), chunk ((g*8 + kc)*16 + rc), byte j.
__device__ __forceinline__ size_t hpk(int m, int k) {
    return (size_t)(m >> 7) * (128 * 768) + (size_t)(k >> 6) * (128 * 64)
         + (size_t)(((((m >> 4) & 7) * 8 + ((k & 63) >> 3)) * 16 + (m & 15)) * 8 + (k & 7));
}

// ---------------------------------------------------------------------------
// Fused prep: weight transposes -> PACKED tile-ready layout (jobs 0..9215),
// interleaved bias pack (9216..9227), LayerNorm1 -> packed h (9228..13323).
// Packed weight layout for block geometry BNt x 64 (K = inner dim):
//   (R, k) -> tileN*BNt*K + (k>>6)*BNt*64 + ((g*8+kc)*16+rc)*8 + j
// ---------------------------------------------------------------------------
__global__ __launch_bounds__(256) void prep_fused(const float* __restrict__ Wq,
                                                  const float* __restrict__ Wk,
                                                  const float* __restrict__ Wv,
                                                  const float* __restrict__ Wo,
                                                  const float* __restrict__ w1,
                                                  const float* __restrict__ w2,
                                                  const float* __restrict__ w3,
                                                  unsigned short* __restrict__ Wqkv_t,
                                                  unsigned short* __restrict__ Wo_t,
                                                  unsigned short* __restrict__ W12_t,
                                                  unsigned short* __restrict__ W3_t,
                                                  const float* __restrict__ b1,
                                                  const float* __restrict__ b2,
                                                  float* __restrict__ b12,
                                                  const float* __restrict__ x,
                                                  const float* __restrict__ g1,
                                                  const float* __restrict__ s1,
                                                  unsigned short* __restrict__ hout) {
    __shared__ float tile[32][33];
    __shared__ float red[4];
    __shared__ float mv[2];
    const int b = blockIdx.x;
    const int tid = threadIdx.x;

    if (b >= 9228) {                      // --- LayerNorm1 -> packed h ---
        const int row = b - 9228;
        const float* xr = x + (size_t)row * D_MODEL;
        float v0 = xr[tid], v1 = xr[tid + 256], v2 = xr[tid + 512];
        float sum = v0 + v1 + v2;
        const int lane = tid & 63, wv = tid >> 6;
        #pragma unroll
        for (int off = 32; off > 0; off >>= 1) sum += __shfl_down(sum, off, 64);
        if (lane == 0) red[wv] = sum;
        __syncthreads();
        if (tid == 0) mv[0] = (red[0] + red[1] + red[2] + red[3]) * (1.0f / D_MODEL);
        __syncthreads();
        const float mean = mv[0];
        float d0 = v0 - mean, d1 = v1 - mean, d2 = v2 - mean;
        float sq = d0 * d0 + d1 * d1 + d2 * d2;
        #pragma unroll
        for (int off = 32; off > 0; off >>= 1) sq += __shfl_down(sq, off, 64);
        if (lane == 0) red[wv] = sq;
        __syncthreads();
        if (tid == 0) mv[1] = (red[0] + red[1] + red[2] + red[3]) * (1.0f / D_MODEL);
        __syncthreads();
        const float rs = rsqrtf(mv[1] + 1e-5f);
        hout[hpk(row, tid)]       = f2bf(g1[tid]       * d0 * rs + s1[tid]);
        hout[hpk(row, tid + 256)] = f2bf(g1[tid + 256] * d1 * rs + s1[tid + 256]);
        hout[hpk(row, tid + 512)] = f2bf(g1[tid + 512] * d2 * rs + s1[tid + 512]);
        return;
    }
    if (b >= 9216) {                      // --- bias pack (16-col interleave) ---
        const int n = (b - 9216) * 256 + tid;
        if (n < FF_DIM) {
            b12[(n >> 4) * 32 + (n & 15)] = b1[n];
            b12[(n >> 4) * 32 + 16 + (n & 15)] = b2[n];
        }
        return;
    }

    // --- weight transpose + pack jobs ---
    const float* W; unsigned short* Wt;
    int K, N, off, ilv, bx, by, BNt;
    if (b < 2304) {                       // jobs 0-3: 576 blocks each (24x24)
        const int j = b / 576, lb = b % 576;
        bx = lb % 24; by = lb / 24;
        K = 768; N = 768; ilv = 0;
        if (j == 0)      { W = Wq; Wt = Wqkv_t; off = 0;    BNt = 128; }
        else if (j == 1) { W = Wk; Wt = Wqkv_t; off = 768;  BNt = 128; }
        else if (j == 2) { W = Wv; Wt = Wqkv_t; off = 1536; BNt = 128; }
        else             { W = Wo; Wt = Wo_t;   off = 0;    BNt = 64;  }
    } else if (b < 6912) {                // jobs 4-5: 2304 blocks each (96x24)
        const int j = (b - 2304) / 2304, lb = (b - 2304) % 2304;
        bx = lb % 96; by = lb / 96;
        K = 768; N = 3072; ilv = 1;
        W = j ? w2 : w1; Wt = W12_t; off = j ? 16 : 0; BNt = 128;
    } else {                              // job 6: 2304 blocks (24x96)
        const int lb = b - 6912;
        bx = lb % 24; by = lb / 24;
        K = 3072; N = 768; ilv = 0;
        W = w3; Wt = W3_t; off = 0; BNt = 64;
    }

    const int tx = tid & 31, ty = tid >> 5;  // 32 x 8
    const int n0 = bx * 32, k0 = by * 32;
    #pragma unroll
    for (int s = 0; s < 32; s += 8)
        tile[ty + s][tx] = W[(size_t)(k0 + ty + s) * N + n0 + tx];
    __syncthreads();
    #pragma unroll
    for (int s = 0; s < 32; s += 8) {
        const int nn = n0 + ty + s;
        const int R = ilv ? ((nn >> 4) * 32 + off + (nn & 15)) : (off + nn);
        const int k = k0 + tx;
        const int Rm = R % BNt;
        const size_t idx = (size_t)(R / BNt) * BNt * K + (size_t)(k >> 6) * BNt * 64
                         + (size_t)((((Rm >> 4) * 8 + ((k & 63) >> 3)) * 16 + (Rm & 15)) * 8 + (k & 7));
        Wt[idx] = f2bf(tile[tx][ty + s]);
    }
}

// ---------------------------------------------------------------------------
// LayerNorm2 (fp32 in) -> PACKED bf16 h2 (BM=128 geometry, consumer FF12)
// ---------------------------------------------------------------------------
__global__ __launch_bounds__(256) void ln_kernel(const float* __restrict__ x,
                                                 const float* __restrict__ g,
                                                 const float* __restrict__ b,
                                                 unsigned short* __restrict__ o) {
    const int row = blockIdx.x;
    const float* xr = x + (size_t)row * D_MODEL;
    const int tid = threadIdx.x;

    float v0 = xr[tid], v1 = xr[tid + 256], v2 = xr[tid + 512];
    float sum = v0 + v1 + v2;

    __shared__ float red[4];
    __shared__ float mv[2];
    const int lane = tid & 63, wv = tid >> 6;

    #pragma unroll
    for (int off = 32; off > 0; off >>= 1) sum += __shfl_down(sum, off, 64);
    if (lane == 0) red[wv] = sum;
    __syncthreads();
    if (tid == 0) mv[0] = (red[0] + red[1] + red[2] + red[3]) * (1.0f / D_MODEL);
    __syncthreads();
    const float mean = mv[0];

    float d0 = v0 - mean, d1 = v1 - mean, d2 = v2 - mean;
    float sq = d0 * d0 + d1 * d1 + d2 * d2;
    #pragma unroll
    for (int off = 32; off > 0; off >>= 1) sq += __shfl_down(sq, off, 64);
    if (lane == 0) red[wv] = sq;
    __syncthreads();
    if (tid == 0) mv[1] = (red[0] + red[1] + red[2] + red[3]) * (1.0f / D_MODEL);
    __syncthreads();
    const float rs = rsqrtf(mv[1] + 1e-5f);

    o[hpk(row, tid)]       = f2bf(g[tid]       * d0 * rs + b[tid]);
    o[hpk(row, tid + 256)] = f2bf(g[tid + 256] * d1 * rs + b[tid + 256]);
    o[hpk(row, tid + 512)] = f2bf(g[tid + 512] * d2 * rs + b[tid + 512]);
}

// ---------------------------------------------------------------------------
// bf16 MFMA GEMM, BK=64, async global_load_lds staging, double-buffered,
// one barrier per iter. B is ALWAYS packed (tile-ready, contiguous staging).
// AP: A packed too (QKV, FF12) — fully-contiguous 1KB/wave-instr DMA.
// EPI=0: C = acc + bias + res -> Cf (fp32) or Cb (bf16), pitch N.
// EPI=1: SwiGLU epilogue on 16-col-interleaved B -> Cb, pitch N/2.
// EPI=2: QKV epilogue — Q/K blocks write Cb (natural); V blocks (bn>=1536)
//        LDS-transpose and write Vt (= (ushort*)Cf) with kl() permutation.
// ---------------------------------------------------------------------------
template<int BM, int BN, int WY, int WX, int MI, int NI, int EPI, bool AP>
__global__ __launch_bounds__(256) void mfma_gemm(const unsigned short* __restrict__ A,
                                                 const unsigned short* __restrict__ Bt,
                                                 const float* __restrict__ bias,
                                                 const float* __restrict__ res,
                                                 float* __restrict__ Cf,
                                                 unsigned short* __restrict__ Cb,
                                                 int M, int N, int K) {
    constexpr int BK = 64;
    constexpr int KC = 8;                 // 16B chunks per row
    constexpr int CA = BM * KC;           // A chunks
    constexpr int CT = (BM + BN) * KC;    // total chunks
    constexpr int SA = CA / 256;
    constexpr int ST = CT / 256;
    __shared__ unsigned short S[2][CT * 8];

    const int t = threadIdx.x;
    const int bn = blockIdx.x * BN;
    const int bm = blockIdx.y * BM;
    const int w = t >> 6, lane = t & 63;
    const int wy = w / WX, wx = w % WX;
    const int quad = lane >> 4, r = lane & 15;

    const unsigned short* gp[ST];
    #pragma unroll
    for (int s = 0; s < ST; ++s) {
        const int c = s * 256 + w * 64 + lane;
        if (s < SA) {
            if (AP) {
                gp[s] = A + (size_t)bm * K + (size_t)c * 8;
            } else {
                const int rc = c & 15, kc = (c >> 4) & 7, g = c >> 7;
                gp[s] = A + (size_t)(bm + g * 16 + rc) * K + kc * 8;
            }
        } else {
            gp[s] = Bt + (size_t)bn * K + (size_t)(c - CA) * 8;
        }
    }

    f32x4 acc[MI][NI];
    const f32x4 fz = {0.f, 0.f, 0.f, 0.f};
    #pragma unroll
    for (int i = 0; i < MI; ++i)
        #pragma unroll
        for (int j = 0; j < NI; ++j) acc[i][j] = fz;

    #pragma unroll
    for (int s = 0; s < ST; ++s)
        gload_lds16(gp[s], &S[0][(s * 256 + w * 64) * 8]);

    const int niter = K / BK;
    for (int it = 0; it < niter; ++it) {
        const int buf = it & 1;
        __syncthreads();            // buf's DMA complete; prior reads done
        if (it + 1 < niter) {
            #pragma unroll
            for (int s = 0; s < ST; ++s) {
                const size_t ko = (s < SA) ? (AP ? (size_t)(it + 1) * BM * 64
                                                 : (size_t)(it + 1) * BK)
                                           : (size_t)(it + 1) * BN * 64;
                gload_lds16(gp[s] + ko, &S[buf ^ 1][(s * 256 + w * 64) * 8]);
            }
        }

        #pragma unroll
        for (int kk = 0; kk < 2; ++kk) {
            bf16x8 af[MI], bfr[NI];
            #pragma unroll
            for (int mi = 0; mi < MI; ++mi)
                af[mi] = *(const bf16x8*)(&S[buf][(((wy * MI + mi) * KC + kk * 4 + quad) * 16 + r) * 8]);
            #pragma unroll
            for (int ni = 0; ni < NI; ++ni)
                bfr[ni] = *(const bf16x8*)(&S[buf][(CA + ((wx * NI + ni) * KC + kk * 4 + quad) * 16 + r) * 8]);
            #pragma unroll
            for (int mi = 0; mi < MI; ++mi)
                #pragma unroll
                for (int ni = 0; ni < NI; ++ni)
                    acc[mi][ni] = mfma16(af[mi], bfr[ni], acc[mi][ni]);
        }
    }

    float bv[NI];
    #pragma unroll
    for (int ni = 0; ni < NI; ++ni)
        bv[ni] = bias ? bias[bn + (wx * NI + ni) * 16 + r] : 0.0f;

    if (EPI == 0) {
        #pragma unroll
        for (int mi = 0; mi < MI; ++mi) {
            #pragma unroll
            for (int i = 0; i < 4; ++i) {
                const int m = bm + (wy * MI + mi) * 16 + quad * 4 + i;
                #pragma unroll
                for (int ni = 0; ni < NI; ++ni) {
                    const int n = bn + (wx * NI + ni) * 16 + r;
                    float v = acc[mi][ni][i] + bv[ni];
                    if (res) v += res[(size_t)m * N + n];
                    if (Cf) Cf[(size_t)m * N + n] = v;
                    else    Cb[(size_t)m * N + n] = f2bf(v);
                }
            }
        }
    } else if (EPI == 1) {
        #pragma unroll
        for (int mi = 0; mi < MI; ++mi) {
            #pragma unroll
            for (int i = 0; i < 4; ++i) {
                const int m = bm + (wy * MI + mi) * 16 + quad * 4 + i;
                #pragma unroll
                for (int p = 0; p < NI / 2; ++p) {
                    float a = acc[mi][2 * p][i] + bv[2 * p];
                    float g = acc[mi][2 * p + 1][i] + bv[2 * p + 1];
                    float uu = a / (1.0f + __expf(-a)) * g;
                    const int n = (bn >> 1) + wx * (NI / 2) * 16 + p * 16 + r;
                    Cb[(size_t)m * (N >> 1) + n] = f2bf(uu);
                }
            }
        }
    } else {  // EPI == 2: QKV with fused V-transpose
        if (bn < 2 * D_MODEL) {
            #pragma unroll
            for (int mi = 0; mi < MI; ++mi) {
                #pragma unroll
                for (int i = 0; i < 4; ++i) {
                    const int m = bm + (wy * MI + mi) * 16 + quad * 4 + i;
                    #pragma unroll
                    for (int ni = 0; ni < NI; ++ni) {
                        const int n = bn + (wx * NI + ni) * 16 + r;
                        Cb[(size_t)m * N + n] = f2bf(acc[mi][ni][i]);
                    }
                }
            }
        } else {
            unsigned short* Vt = (unsigned short*)Cf;
            unsigned short* TB = &S[0][0];           // need 64*132 = 8448 shorts
            const int vc0 = bn - 2 * D_MODEL;
            #pragma unroll
            for (int g = 0; g < 2; ++g) {
                __syncthreads();
                if (wy == g) {
                    #pragma unroll
                    for (int mi = 0; mi < MI; ++mi)
                        #pragma unroll
                        for (int i = 0; i < 4; ++i)
                            #pragma unroll
                            for (int ni = 0; ni < NI; ++ni)
                                TB[(mi * 16 + quad * 4 + i) * 132 + wx * 64 + ni * 16 + r] =
                                    f2bf(acc[mi][ni][i]);
                }
                __syncthreads();
                const int c = t >> 1, s0 = (t & 1) * 32;
                unsigned short ob[32];
                #pragma unroll
                for (int j = 0; j < 32; ++j) {
                    const int s = s0 + j;
                    ob[j] = TB[((s & 3) * 16 + (s >> 2)) * 132 + c];
                }
                unsigned short* dst = Vt + (size_t)(vc0 + c) * T_SEQ + bm + g * 64 + s0;
                #pragma unroll
                for (int j = 0; j < 32; j += 8)
                    *(uint4*)(dst + j) = *(uint4*)(ob + j);
            }
        }
    }
}

// ---------------------------------------------------------------------------
// Softmax step, 2 M-fragments (32 q-rows/wave), fixed-max: p = exp(s),
// masked -> 0. b64 P writes with XOR bank swizzle; per-mi 1024-short region.
// ---------------------------------------------------------------------------
template <bool DIAG>
__device__ __forceinline__ void softmax_step2(const f32x4 sacc[2][4],
                                              unsigned short* __restrict__ Pw,
                                              int k0, int qg0, int r, int quad) {
    const int rp = r >> 1;
    const int cbase = (r >> 3) * 64 + ((r >> 1) & 3) * 16;
    #pragma unroll
    for (int mi = 0; mi < 2; ++mi) {
        unsigned short* Pm = Pw + mi * 1024;
        #pragma unroll
        for (int i = 0; i < 4; ++i) {
            unsigned int pk[2];
            #pragma unroll
            for (int ni = 0; ni < 4; ++ni) {
                float p = __expf(sacc[mi][ni][i]);
                if (DIAG) { if (k0 + ni * 16 + r > qg0 + mi * 16 + i) p = 0.0f; }
                const unsigned int pb = (__float_as_uint(p) + 0x8000u) >> 16;
                if (ni & 1) pk[ni >> 1] |= pb << 16;
                else        pk[ni >> 1] = pb;
            }
            const int rrp = (quad * 4 + i) ^ rp;
            uint2 wv; wv.x = pk[0]; wv.y = pk[1];
            *(uint2*)(&Pm[(cbase + rrp) * 8 + 4 * (r & 1)]) = wv;
        }
    }
}

// ---------------------------------------------------------------------------
// Flash attention partial: 128 q-rows per block (wave = 32 rows), K-split
// into chunks of <=8 k-tiles. Partial O bf16 + l fp32 to workspace.
// ---------------------------------------------------------------------------
__global__ __launch_bounds__(256) void attn_partial(const unsigned short* __restrict__ qkv,
                                                    const unsigned short* __restrict__ Vt,
                                                    unsigned short* __restrict__ part) {
    const int h = blockIdx.y;
    int b = (int)blockIdx.x, qt = 31, ci = 0;
    for (int q = 31; q >= 0; --q) {          // longest q-tiles first
        const int nc = (2 * q + 9) >> 3;     // ceil((2q+2)/8)
        if (b < nc) { qt = q; ci = b; break; }
        b -= nc;
    }
    const int q0 = qt * 128;
    const int kb = ci * KCHUNK;
    const int nt = min(KCHUNK, 2 * qt + 2 - kb);

    const int t = threadIdx.x;
    const int w = t >> 6, lane = t & 63;
    const int quad = lane >> 4, r = lane & 15;

    __shared__ unsigned short Ks[2][4096];
    __shared__ unsigned short Vs[2][4096];
    __shared__ unsigned short Ps[4][2048];

    bf16x8 aq[2][2];   // [ks][mi]
    #pragma unroll
    for (int mi = 0; mi < 2; ++mi) {
        const unsigned short* qp = qkv + (size_t)(q0 + w * 32 + mi * 16 + r) * QKV_LD + h * 64 + quad * 8;
        uint4 q0v = *(const uint4*)(qp);
        uint4 q1v = *(const uint4*)(qp + 32);
        const unsigned short* p0 = (const unsigned short*)&q0v;
        const unsigned short* p1 = (const unsigned short*)&q1v;
        #pragma unroll
        for (int j = 0; j < 8; ++j) {
            aq[0][mi][j] = (__bf16)(bf2f(p0[j]) * 0.125f);
            aq[1][mi][j] = (__bf16)(bf2f(p1[j]) * 0.125f);
        }
    }

    bf16x8 ones;
    #pragma unroll
    for (int j = 0; j < 8; ++j) ones[j] = (__bf16)1.0f;

    const int rc = lane & 15, qc = (lane >> 4) & 3;
    const unsigned short* kg0 = qkv + (size_t)(kb * 64 + w * 16 + rc) * QKV_LD + D_MODEL + h * 64 + qc * 8;
    const unsigned short* kg1 = kg0 + 32;
    const unsigned short* vg0 = Vt + (size_t)(h * 64 + w * 16 + rc) * T_SEQ + kb * 64 + qc * 8;
    const unsigned short* vg1 = vg0 + 32;
    const int l0 = (w * 64) * 8, l1 = (256 + w * 64) * 8;

    const f32x4 fz = {0.f, 0.f, 0.f, 0.f};
    f32x4 acc_o[2][4] = {{fz, fz, fz, fz}, {fz, fz, fz, fz}};
    f32x4 acc_l[2] = {fz, fz};
    const int qg0 = q0 + w * 32 + quad * 4;

    gload_lds16(kg0, &Ks[0][l0]);
    gload_lds16(kg1, &Ks[0][l1]);
    gload_lds16(vg0, &Vs[0][l0]);
    gload_lds16(vg1, &Vs[0][l1]);

    for (int lt = 0; lt < nt; ++lt) {
        const int kt = kb + lt;
        const int buf = lt & 1;
        __syncthreads();
        if (lt + 1 < nt) {
            const size_t kofs = (size_t)(lt + 1) * 64;
            gload_lds16(kg0 + kofs * QKV_LD, &Ks[buf ^ 1][l0]);
            gload_lds16(kg1 + kofs * QKV_LD, &Ks[buf ^ 1][l1]);
            gload_lds16(vg0 + kofs, &Vs[buf ^ 1][l0]);
            gload_lds16(vg1 + kofs, &Vs[buf ^ 1][l1]);
        }

        f32x4 sacc[2][4] = {{fz, fz, fz, fz}, {fz, fz, fz, fz}};
        #pragma unroll
        for (int ks = 0; ks < 2; ++ks)
            #pragma unroll
            for (int ni = 0; ni < 4; ++ni) {
                bf16x8 bk = *(const bf16x8*)(&Ks[buf][((ks * 4 + ni) * 64 + lane) * 8]);
                sacc[0][ni] = mfma16(aq[ks][0], bk, sacc[0][ni]);
                sacc[1][ni] = mfma16(aq[ks][1], bk, sacc[1][ni]);
            }

        const int k0 = kt * 64;
        if (kt >= 2 * qt)
            softmax_step2<true >(sacc, Ps[w], k0, qg0, r, quad);
        else
            softmax_step2<false>(sacc, Ps[w], k0, qg0, r, quad);

        const int kqr = lane >> 4, rrr = lane & 15;
        #pragma unroll
        for (int ks = 0; ks < 2; ++ks) {
            const int pc = ks * 64 + kqr * 16 + (rrr ^ (ks * 4 + kqr));
            bf16x8 ap0 = *(const bf16x8*)(&Ps[w][pc * 8]);
            bf16x8 ap1 = *(const bf16x8*)(&Ps[w][1024 + pc * 8]);
            #pragma unroll
            for (int nd = 0; nd < 4; ++nd) {
                bf16x8 bv = *(const bf16x8*)(&Vs[buf][((ks * 4 + nd) * 64 + lane) * 8]);
                acc_o[0][nd] = mfma16(ap0, bv, acc_o[0][nd]);
                acc_o[1][nd] = mfma16(ap1, bv, acc_o[1][nd]);
            }
            acc_l[0] = mfma16(ap0, ones, acc_l[0]);
            acc_l[1] = mfma16(ap1, ones, acc_l[1]);
        }
    }

    unsigned short* pb = part + ((size_t)(qt * N_HEADS + h) * KCHUNK + ci) * PSH;
    float* pl = (float*)(pb + 8192);
    #pragma unroll
    for (int mi = 0; mi < 2; ++mi) {
        #pragma unroll
        for (int i = 0; i < 4; ++i) {
            const int row = w * 32 + mi * 16 + quad * 4 + i;
            unsigned short ob[4];
            #pragma unroll
            for (int nd = 0; nd < 4; ++nd) ob[nd] = f2bf(acc_o[mi][nd][i]);
            *(uint2*)(pb + row * 64 + r * 4) = *(uint2*)ob;
            if (r == 0) pl[row] = acc_l[mi][i];
        }
    }
}

// ---------------------------------------------------------------------------
// Merge partials (bf16 O, fp32 l): ctx = (sum O) / (sum l). grid (32, 12).
// ---------------------------------------------------------------------------
__global__ __launch_bounds__(256) void attn_merge(const unsigned short* __restrict__ part,
                                                  unsigned short* __restrict__ ctx) {
    const int qt = blockIdx.x, h = blockIdx.y;
    const int nc = (2 * qt + 9) >> 3;
    const int t = threadIdx.x;
    const int row = t >> 1, half = t & 1, cp0 = half * 32;

    float o[32];
    #pragma unroll
    for (int j = 0; j < 32; ++j) o[j] = 0.0f;
    float l = 0.0f;

    for (int ci = 0; ci < nc; ++ci) {
        const unsigned short* pb = part + ((size_t)(qt * N_HEADS + h) * KCHUNK + ci) * PSH;
        l += ((const float*)(pb + 8192))[row];
        #pragma unroll
        for (int j0 = 0; j0 < 32; j0 += 8) {
            uint4 v = *(const uint4*)(pb + row * 64 + cp0 + j0);
            const unsigned short* pv = (const unsigned short*)&v;
            #pragma unroll
            for (int j = 0; j < 8; ++j) o[j0 + j] += bf2f(pv[j]);
        }
    }
    const float inv = 1.0f / l;
    unsigned short* base = ctx + (size_t)(qt * 128 + row) * D_MODEL + h * 64;
    #pragma unroll
    for (int p = 0; p < 4; ++p) {
        unsigned short ob[8];
        #pragma unroll
        for (int q = 0; q < 8; ++q) ob[q] = f2bf(o[q * 4 + p] * inv);
        *(uint4*)(base + p * 16 + half * 8) = *(uint4*)ob;
    }
}

// ---------------------------------------------------------------------------
// launch
// ---------------------------------------------------------------------------
extern "C" void kernel_launch(void* const* d_in, const int* in_sizes, int n_in,
                              void* d_out, int out_size, void* d_ws, size_t ws_size,
                              hipStream_t stream) {
    const float* x  = (const float*)d_in[0];
    const float* Wq = (const float*)d_in[1];
    const float* Wk = (const float*)d_in[2];
    const float* Wv = (const float*)d_in[3];
    const float* Wo = (const float*)d_in[4];
    const float* bo = (const float*)d_in[5];
    const float* w1 = (const float*)d_in[6];
    const float* b1 = (const float*)d_in[7];
    const float* w2 = (const float*)d_in[8];
    const float* b2 = (const float*)d_in[9];
    const float* w3 = (const float*)d_in[10];
    const float* b3 = (const float*)d_in[11];
    const float* g1 = (const float*)d_in[12];
    const float* s1 = (const float*)d_in[13];
    const float* g2 = (const float*)d_in[14];
    const float* s2 = (const float*)d_in[15];
    float* out = (float*)d_out;

    const size_t TD = (size_t)T_SEQ * D_MODEL;

    char* p = (char*)d_ws;
    auto alloc = [&](size_t bytes) { char* r = p; p += (bytes + 255) & ~(size_t)255; return r; };
    // persistent region (live across attention)
    unsigned short* qkv    = (unsigned short*)alloc((size_t)T_SEQ * QKV_LD * 2);
    unsigned short* Vtb    = (unsigned short*)alloc((size_t)D_MODEL * T_SEQ * 2);
    unsigned short* ctx    = (unsigned short*)alloc(TD * 2);
    unsigned short* Wqkv_t = (unsigned short*)alloc((size_t)QKV_LD * D_MODEL * 2);
    unsigned short* Wo_t   = (unsigned short*)alloc((size_t)D_MODEL * D_MODEL * 2);
    unsigned short* W12_t  = (unsigned short*)alloc((size_t)AG_LD * D_MODEL * 2);
    unsigned short* W3_t   = (unsigned short*)alloc((size_t)D_MODEL * FF_DIM * 2);
    float*          b12    = (float*)alloc((size_t)AG_LD * 4);
    // overlay region: part aliases {h, x2, h2, u} (lifetime-disjoint).
    const size_t part_bytes = (size_t)32 * N_HEADS * KCHUNK * PSH * 2;   // 51.9 MB
    const size_t overlay_bytes = ((TD * 2 + 255) & ~(size_t)255) + ((TD * 4 + 255) & ~(size_t)255)
                               + ((TD * 2 + 255) & ~(size_t)255) + (size_t)T_SEQ * FF_DIM * 2;
    char* R = alloc(part_bytes > overlay_bytes ? part_bytes : overlay_bytes);
    unsigned short* part = (unsigned short*)R;
    unsigned short* h    = (unsigned short*)R;
    float*          x2   = (float*)(R + ((TD * 2 + 255) & ~(size_t)255));
    unsigned short* h2   = (unsigned short*)((char*)x2 + ((TD * 4 + 255) & ~(size_t)255));
    unsigned short* u    = (unsigned short*)((char*)h2 + ((TD * 2 + 255) & ~(size_t)255));

    // --- fused prep: packed weight transposes + bias pack + LN1 (packed h) ---
    prep_fused<<<13324, 256, 0, stream>>>(Wq, Wk, Wv, Wo, w1, w2, w3,
                                          Wqkv_t, Wo_t, W12_t, W3_t,
                                          b1, b2, b12, x, g1, s1, h);

    // QKV: packed A + packed B; V blocks write Vtb transposed (EPI=2)
    mfma_gemm<128, 128, 2, 2, 4, 4, 2, true><<<dim3(QKV_LD / 128, T_SEQ / 128), 256, 0, stream>>>(
        h, Wqkv_t, nullptr, nullptr, (float*)Vtb, qkv, T_SEQ, QKV_LD, D_MODEL);

    // attention: 144 chunks/head (128-q-row tiles, 8-k-tile chunks)
    attn_partial<<<dim3(144, N_HEADS), 256, 0, stream>>>(qkv, Vtb, part);
    attn_merge<<<dim3(T_SEQ / 128, N_HEADS), 256, 0, stream>>>(part, ctx);

    // Wo: natural A (ctx) + packed B
    mfma_gemm<64, 64, 2, 2, 2, 2, 0, false><<<dim3(D_MODEL / 64, T_SEQ / 64), 256, 0, stream>>>(
        ctx, Wo_t, bo, x, x2, nullptr, T_SEQ, D_MODEL, D_MODEL);

    ln_kernel<<<T_SEQ, 256, 0, stream>>>(x2, g2, s2, h2);

    // FF1+FF2 fused SwiGLU: packed A (h2) + packed B
    mfma_gemm<128, 128, 2, 2, 4, 4, 1, true><<<dim3(AG_LD / 128, T_SEQ / 128), 256, 0, stream>>>(
        h2, W12_t, b12, nullptr, nullptr, u, T_SEQ, AG_LD, D_MODEL);

    // FF3: natural A (u) + packed B
    mfma_gemm<64, 64, 2, 2, 2, 2, 0, false><<<dim3(D_MODEL / 64, T_SEQ / 64), 256, 0, stream>>>(
        u, W3_t, b3, x2, out, nullptr, T_SEQ, D_MODEL, FF_DIM);
}